// Round 14
// baseline (445.256 us; speedup 1.0000x reference)
//
#include <hip/hip_runtime.h>
#include <hip/hip_bf16.h>
#include <cstdint>

typedef unsigned short u16;
typedef u16  u16x8 __attribute__((ext_vector_type(8)));
typedef short s16x8 __attribute__((ext_vector_type(8)));
typedef float f32x4 __attribute__((ext_vector_type(4)));

#define PI_F 3.14159265358979323846f
#define PD(i) ((i) + 3 * ((i) >> 5))

static __device__ __forceinline__ u16 f2bf(float f) {
    union { float f; unsigned u; } v; v.f = f;
    unsigned r = v.u + 0x7fffu + ((v.u >> 16) & 1u);
    return (u16)(r >> 16);
}
static __device__ __forceinline__ float bf2f(u16 h) {
    union { unsigned u; float f; } v; v.u = ((unsigned)h) << 16;
    return v.f;
}

__device__ __forceinline__ void gl_lds16(const u16* g, u16* l) {
    __builtin_amdgcn_global_load_lds(
        (const __attribute__((address_space(1))) unsigned int*)g,
        (__attribute__((address_space(3))) unsigned int*)l, 16, 0, 0);
}

// ---------------------------------------------------------------------------
// f32 -> bf16 convert, 3 tensors in one dispatch
// ---------------------------------------------------------------------------
__global__ __launch_bounds__(256) void cvt3(const float* __restrict__ q,
                                            const float* __restrict__ k,
                                            const float* __restrict__ v,
                                            u16* __restrict__ out, int n8) {
    int i = blockIdx.x * 256 + threadIdx.x;
    if (i >= n8) return;
    const float* in = (blockIdx.y == 0) ? q : (blockIdx.y == 1) ? k : v;
    u16* o = out + (size_t)blockIdx.y * 8192 * 512;
    float4 a = ((const float4*)in)[2 * i];
    float4 b = ((const float4*)in)[2 * i + 1];
    u16x8 vv;
    vv[0] = f2bf(a.x); vv[1] = f2bf(a.y); vv[2] = f2bf(a.z); vv[3] = f2bf(a.w);
    vv[4] = f2bf(b.x); vv[5] = f2bf(b.y); vv[6] = f2bf(b.z); vv[7] = f2bf(b.w);
    ((u16x8*)o)[i] = vv;
}

// ---------------------------------------------------------------------------
// Expand quaternion weights (3 per dispatch via blockIdx.y)
// ---------------------------------------------------------------------------
template<int LOGK>
__global__ void build_E3(const float* __restrict__ W0, const float* __restrict__ W1,
                         const float* __restrict__ W2, u16* __restrict__ E0,
                         u16* __restrict__ E1, u16* __restrict__ E2) {
    const int K = 1 << LOGK;
    int idx = blockIdx.x * 256 + threadIdx.x;
    if (idx >= (2048 << LOGK)) return;
    const float* W = (blockIdx.y == 0) ? W0 : (blockIdx.y == 1) ? W1 : W2;
    u16* E = (blockIdx.y == 0) ? E0 : (blockIdx.y == 1) ? E1 : E2;
    int n = idx >> LOGK, k = idx & (K - 1);
    int o = n >> 2, c = n & 3, i = k >> 2, cp = k & 3;
    const int   qm[4][4] = {{0,1,2,3},{1,0,3,2},{2,3,0,1},{3,2,1,0}};
    const float qs[4][4] = {{1.f,-1.f,-1.f,-1.f},{1.f,1.f,1.f,-1.f},
                            {1.f,-1.f,1.f,1.f},{1.f,1.f,-1.f,1.f}};
    int in_q = K >> 2;
    float w = W[(size_t)qm[c][cp] * 512 * in_q + (size_t)o * in_q + i] * qs[c][cp];
    E[idx] = f2bf(w);
}

// ---------------------------------------------------------------------------
// Tables: per-pass twiddle sub-tables + phases.
// ---------------------------------------------------------------------------
__global__ __launch_bounds__(256) void build_tabs(float2* __restrict__ gws,
                                                  float* __restrict__ ph) {
    int i = blockIdx.x * 256 + threadIdx.x;
    if (i < 682) {
        int off, lh;
        if (i < 2)        { off = 0;   lh = 1; }
        else if (i < 10)  { off = 2;   lh = 3; }
        else if (i < 42)  { off = 10;  lh = 5; }
        else if (i < 170) { off = 42;  lh = 7; }
        else              { off = 170; lh = 9; }
        int j = i - off;
        float a = (-PI_F) * (float)j / (float)(2 << lh);
        gws[i] = make_float2(cosf(a), sinf(a));
    }
    if (i <= 1024) {
        ph[i] = atanf(logf((float)i * (1.0f / 2048.0f) + 1e-6f));
    }
}

// ---------------------------------------------------------------------------
// Bias matvec: out[n] = sum_k v[k]*E[n][k] + badd[n]
// ---------------------------------------------------------------------------
__global__ __launch_bounds__(256) void matvec_E(const float* __restrict__ v,
                                                const u16* __restrict__ E,
                                                const float* __restrict__ badd,
                                                float* __restrict__ out) {
    int n    = (blockIdx.x * 256 + threadIdx.x) >> 6;
    int lane = threadIdx.x & 63;
    if (n >= 2048) return;
    const u16* row = E + (size_t)n * 2048;
    float s = 0.f;
    for (int j = lane; j < 2048; j += 64) s += v[j] * bf2f(row[j]);
#pragma unroll
    for (int o = 32; o; o >>= 1) s += __shfl_down(s, o, 64);
    if (lane == 0) out[n] = s + badd[n];
}

// ---------------------------------------------------------------------------
// bf16 MFMA GEMM body (m97 structure + XCD super-tiles). NBX=16, NBY=M/128.
// OUTMODE 0: bf16 [m][n]; 1: f32 [m][n]; 2: bf16 transposed [n][m]/[b][n][s]
// ---------------------------------------------------------------------------
template<int K, int OUTMODE, int NBY>
__device__ __forceinline__ void gemm_body(int bid, u16* As, u16* Bs,
                                          const u16* __restrict__ A,
                                          const u16* __restrict__ E,
                                          const float* __restrict__ bias,
                                          void* __restrict__ outp) {
    const int t    = threadIdx.x;
    const int lane = t & 63, wave = t >> 6;
    const int wr   = wave >> 1, wc = wave & 1;
    const int lr   = lane & 15, kg = lane >> 4;
    const int l7   = lr & 7;

    constexpr int SPX = (4 * (NBY / 4)) / 8;
    const int xcd = bid & 7, p = bid >> 3;
    const int st  = xcd * SPX + (p >> 4);
    const int w   = p & 15;
    const int bx  = (st & 3) * 4 + (w & 3);
    const int by  = (st >> 2) * 4 + (w >> 2);
    const int m0  = by * 128;
    const int n0  = bx * 128;

    f32x4 acc[4][4];
#pragma unroll
    for (int i = 0; i < 4; ++i)
#pragma unroll
        for (int j = 0; j < 4; ++j) acc[i][j] = (f32x4){0.f, 0.f, 0.f, 0.f};

    const int arow = wr * 64 + lr;
    const int brow = wc * 64 + lr;

    for (int k0 = 0; k0 < K; k0 += 64) {
#pragma unroll
        for (int c = 0; c < 4; ++c) {
            int idx = t + c * 256;
            int row = idx >> 3, sl = idx & 7;
            int gsl = sl ^ (row & 7);
            gl_lds16(A + (size_t)(m0 + row) * K + k0 + gsl * 8, &As[idx * 8]);
            gl_lds16(E + (size_t)(n0 + row) * K + k0 + gsl * 8, &Bs[idx * 8]);
        }
        __syncthreads();
#pragma unroll
        for (int ks = 0; ks < 2; ++ks) {
            const int slot = (ks * 4 + kg) ^ l7;
            s16x8 av[4], bv[4];
#pragma unroll
            for (int mi = 0; mi < 4; ++mi)
                av[mi] = *(const s16x8*)&As[(arow + mi * 16) * 64 + slot * 8];
#pragma unroll
            for (int ni = 0; ni < 4; ++ni)
                bv[ni] = *(const s16x8*)&Bs[(brow + ni * 16) * 64 + slot * 8];
#pragma unroll
            for (int mi = 0; mi < 4; ++mi)
#pragma unroll
                for (int ni = 0; ni < 4; ++ni)
                    acc[mi][ni] = __builtin_amdgcn_mfma_f32_16x16x32_bf16(
                        av[mi], bv[ni], acc[mi][ni], 0, 0, 0);
        }
        __syncthreads();
    }

#pragma unroll
    for (int ni = 0; ni < 4; ++ni) {
        int n = n0 + wc * 64 + ni * 16 + lr;
        float bvl = bias ? bias[n] : 0.0f;
#pragma unroll
        for (int mi = 0; mi < 4; ++mi) {
#pragma unroll
            for (int r = 0; r < 4; ++r) {
                int m = m0 + wr * 64 + mi * 16 + kg * 4 + r;
                float val = acc[mi][ni][r] + bvl;
                if constexpr (OUTMODE == 0) {
                    ((u16*)outp)[(size_t)m * 2048 + n] = f2bf(val);
                } else if constexpr (OUTMODE == 1) {
                    ((float*)outp)[(size_t)m * 2048 + n] = val;
                } else {
                    int b = m >> 11, s = m & 2047;
                    ((u16*)outp)[((size_t)b * 2048 + n) * 2048 + s] = f2bf(val);
                }
            }
        }
    }
}

template<int K, int OUTMODE, int NBY>
__global__ __launch_bounds__(256) void gemm2(const u16* __restrict__ A,
                                             const u16* __restrict__ E,
                                             const float* __restrict__ bias,
                                             void* __restrict__ outp) {
    __shared__ u16 As[128 * 64];
    __shared__ u16 Bs[128 * 64];
    gemm_body<K, OUTMODE, NBY>(blockIdx.x, As, Bs, A, E, bias, outp);
}

// Layer-1 fat kernel: combine1 (256, 1-per-13) + projQ/projK/projV (3072)
__global__ __launch_bounds__(256) void fat_mm(const u16* __restrict__ Aq,
                                              const u16* __restrict__ Eq,
                                              const float* __restrict__ bq,
                                              void* __restrict__ Qt,
                                              const u16* __restrict__ Ak,
                                              const u16* __restrict__ Ek,
                                              const float* __restrict__ bk,
                                              void* __restrict__ Kt,
                                              const u16* __restrict__ Av,
                                              const u16* __restrict__ Ev,
                                              const float* __restrict__ bvb,
                                              void* __restrict__ Vt,
                                              const u16* __restrict__ Efin,
                                              const u16* __restrict__ EintT,
                                              void* __restrict__ T1T) {
    __shared__ u16 As[128 * 64];
    __shared__ u16 Bs[128 * 64];
    int bid = blockIdx.x;
    int q = bid / 13, r = bid % 13;
    if (r == 12) {
        gemm_body<2048, 2, 16>(q, As, Bs, Efin, EintT, nullptr, T1T);
    } else {
        int pid = q * 12 + r;                 // [0, 3072)
        int which = pid >> 10, pbid = pid & 1023;
        if (which == 0)
            gemm_body<512, 2, 64>(pbid, As, Bs, Aq, Eq, bq, Qt);
        else if (which == 1)
            gemm_body<512, 2, 64>(pbid, As, Bs, Ak, Ek, bk, Kt);
        else
            gemm_body<512, 2, 64>(pbid, As, Bs, Av, Ev, bvb, Vt);
    }
}

// ---------------------------------------------------------------------------
// In-place FFT, bitrev input -> natural output. Radix-2 + radix-4 passes.
// ---------------------------------------------------------------------------
template<int LH, int OFF>
__device__ __forceinline__ void r4pass(float* re, float* im,
                                       const float2* __restrict__ wt, int t) {
    constexpr int h = 1 << LH;
    __syncthreads();
#pragma unroll
    for (int u = 0; u < 2; ++u) {
        int vidx = t + u * 256;
        int j = vidx & (h - 1);
        int i0 = ((vidx >> LH) << (LH + 2)) | j;
        float2 w2 = wt[OFF + j];
        float w1r = w2.x * w2.x - w2.y * w2.y;
        float w1i = 2.f * w2.x * w2.y;
        float w3r = w2.y, w3i = -w2.x;
        int p0 = PD(i0), p1 = PD(i0 + h), p2 = PD(i0 + 2 * h), p3 = PD(i0 + 3 * h);
        float ar = re[p0], ai = im[p0];
        float br = re[p1], bi = im[p1];
        float cr = re[p2], ci = im[p2];
        float dr = re[p3], di = im[p3];
        float tbr = w1r * br - w1i * bi, tbi = w1r * bi + w1i * br;
        float tdr = w1r * dr - w1i * di, tdi = w1r * di + w1i * dr;
        float a1r = ar + tbr, a1i = ai + tbi;
        float b1r = ar - tbr, b1i = ai - tbi;
        float c1r = cr + tdr, c1i = ci + tdi;
        float d1r = cr - tdr, d1i = ci - tdi;
        float tcr = w2.x * c1r - w2.y * c1i, tci = w2.x * c1i + w2.y * c1r;
        float ter = w3r * d1r - w3i * d1i, tei = w3r * d1i + w3i * d1r;
        re[p0] = a1r + tcr; im[p0] = a1i + tci;
        re[p2] = a1r - tcr; im[p2] = a1i - tci;
        re[p1] = b1r + ter; im[p1] = b1i + tei;
        re[p3] = b1r - ter; im[p3] = b1i - tei;
    }
}

__device__ void fft2048(float* re, float* im, const float2* __restrict__ wt, int t) {
    __syncthreads();
#pragma unroll
    for (int u = 0; u < 4; ++u) {
        int i0 = 2 * (t + u * 256);
        int p0 = PD(i0), p1 = p0 + 1;
        float ar = re[p0], ai = im[p0];
        float br = re[p1], bi = im[p1];
        re[p0] = ar + br; im[p0] = ai + bi;
        re[p1] = ar - br; im[p1] = ai - bi;
    }
    r4pass<1, 0>(re, im, wt, t);
    r4pass<3, 2>(re, im, wt, t);
    r4pass<5, 10>(re, im, wt, t);
    r4pass<7, 42>(re, im, wt, t);
    r4pass<9, 170>(re, im, wt, t);
    __syncthreads();
}

// ---------------------------------------------------------------------------
// Spectral body: 2 channels, packed FFTs; writes WEIGHTS to Wt.
// Wt may alias Qt: each block reads ONLY its own 2 channels (fully consumed
// before the final write) and writes ONLY those same 2 channels.
// ---------------------------------------------------------------------------
__device__ void spectral_body(int sbid, float* zre, float* zim, float2* wt,
                              const u16* __restrict__ Qt,
                              const u16* __restrict__ Kt,
                              u16* __restrict__ Wt,
                              const float* __restrict__ alpha,
                              const float2* __restrict__ gws,
                              const float* __restrict__ gph) {
    const int t  = threadIdx.x;
    const int b  = sbid >> 10;
    const int cp = sbid & 1023;
    const int c0 = cp * 2;
    const size_t base0 = ((size_t)b * 2048 + c0) * 2048;
    const size_t base1 = base0 + 2048;

    for (int i = t; i < 682; i += 256) wt[i] = gws[i];

    float ph[4];
    float PH1r[4], PH1i[4], PH2r[4], PH2i[4];
    float ph24 = 0.f, PH24_1 = 0.f, PH24_2 = 0.f;

#pragma unroll
    for (int ch = 0; ch < 2; ++ch) {
        const size_t base = ch ? base1 : base0;
        const u16* Qp = Qt + base;
        const u16* Kp = Kt + base;
        __syncthreads();
#pragma unroll
        for (int u = 0; u < 8; ++u) {
            int s = t + u * 256;
            int r = __brev((unsigned)s) >> 21;
            zre[PD(r)] = bf2f(Qp[s]);
            zim[PD(r)] = bf2f(Kp[s]);
        }
        fft2048(zre, zim, wt, t);
        const float ac = alpha[c0 + ch];
#pragma unroll
        for (int u = 0; u < 4; ++u) {
            int k = t + u * 256;
            int m = (2048 - k) & 2047;
            float ar = zre[PD(k)], ai = zim[PD(k)];
            float br = zre[PD(m)], bi = zim[PD(m)];
            float qr = 0.5f * (ar + br), qi = 0.5f * (ai - bi);
            float kr = 0.5f * (ai + bi), ki = 0.5f * (br - ar);
            float cr = qr * kr + qi * ki;
            float ci = qi * kr - qr * ki;
            if (ch == 0) ph[u] = gph[min(k, 2048 - k)];
            float fr, fi;
            __sincosf(ph[u] * ac, &fi, &fr);
            float Pkr = cr * fr - ci * fi, Pki = cr * fi + ci * fr;
            float qr2 = 0.5f * (br + ar), qi2 = 0.5f * (bi - ai);
            float kr2 = 0.5f * (bi + ai), ki2 = 0.5f * (ar - br);
            float cr2 = qr2 * kr2 + qi2 * ki2;
            float ci2 = qi2 * kr2 - qr2 * ki2;
            float Pmr = cr2 * fr - ci2 * fi, Pmi = cr2 * fi + ci2 * fr;
            float hr = 0.5f * (Pkr + Pmr), hi = 0.5f * (Pki - Pmi);
            if (ch == 0) { PH1r[u] = hr; PH1i[u] = hi; }
            else         { PH2r[u] = hr; PH2i[u] = hi; }
        }
        if (t == 0) {
            float ar = zre[PD(1024)], ai = zim[PD(1024)];
            float cr = ar * ai;
            if (ch == 0) ph24 = gph[1024];
            float fr, fi;
            __sincosf(ph24 * ac, &fi, &fr);
            if (ch == 0) PH24_1 = cr * fr; else PH24_2 = cr * fr;
        }
    }

    __syncthreads();
#pragma unroll
    for (int u = 0; u < 4; ++u) {
        int k = t + u * 256;
        int m = (2048 - k) & 2047;
        int rk = __brev((unsigned)k) >> 21;
        int rm = __brev((unsigned)m) >> 21;
        zre[PD(rk)] = PH1r[u] - PH2i[u];
        zim[PD(rk)] = PH1i[u] + PH2r[u];
        zre[PD(rm)] = PH1r[u] + PH2i[u];
        zim[PD(rm)] = PH2r[u] - PH1i[u];
    }
    if (t == 0) {
        zre[PD(1)] = PH24_1;
        zim[PD(1)] = PH24_2;
    }
    fft2048(zre, zim, wt, t);

#pragma unroll
    for (int u = 0; u < 8; ++u) {
        int s = t + u * 256;
        int j = (2048 - s) & 2047;
        Wt[base0 + s] = f2bf(zre[PD(j)] * (1.0f / 2048.0f));
        Wt[base1 + s] = f2bf(zim[PD(j)] * (1.0f / 2048.0f));
    }
}

// Layer-2 fat kernel: spectral (4096) + combine2 (256), interleaved 16:1.
__global__ __launch_bounds__(256) void fat_spec2(const u16* __restrict__ Qt,
                                                 const u16* __restrict__ Kt,
                                                 u16* __restrict__ Wt,
                                                 const float* __restrict__ alpha,
                                                 const float2* __restrict__ gws,
                                                 const float* __restrict__ gph,
                                                 const u16* __restrict__ Eout,
                                                 const u16* __restrict__ T1T,
                                                 void* __restrict__ Ecomb) {
    __shared__ __align__(16) char smem[32768];
    int bid = blockIdx.x;
    int q = bid / 17, r = bid % 17;
    if (r == 16) {
        gemm_body<2048, 0, 16>(q, (u16*)smem, (u16*)(smem + 16384),
                               Eout, T1T, nullptr, Ecomb);
    } else {
        int sbid = q * 16 + r;
        spectral_body(sbid, (float*)smem, (float*)(smem + 8960),
                      (float2*)(smem + 17920), Qt, Kt, Wt, alpha, gws, gph);
    }
}

// ---------------------------------------------------------------------------
// Plain transpose (EintT) and fused multiply-transpose (attn = (W .* V)^T)
// ---------------------------------------------------------------------------
__global__ __launch_bounds__(256) void transpose_k(const u16* __restrict__ in,
                                                   u16* __restrict__ out) {
    __shared__ u16 tile[32][33];
    int b = blockIdx.z;
    int c0 = blockIdx.x * 32, s0 = blockIdx.y * 32;
    int tx = threadIdx.x, ty = threadIdx.y;
#pragma unroll
    for (int dy = 0; dy < 32; dy += 8)
        tile[ty + dy][tx] = in[((size_t)b * 2048 + c0 + ty + dy) * 2048 + s0 + tx];
    __syncthreads();
#pragma unroll
    for (int dy = 0; dy < 32; dy += 8)
        out[((size_t)b * 2048 + s0 + ty + dy) * 2048 + c0 + tx] = tile[tx][ty + dy];
}

__global__ __launch_bounds__(256) void transpose_mul(const u16* __restrict__ W,
                                                     const u16* __restrict__ V,
                                                     u16* __restrict__ out) {
    __shared__ u16 tile[32][33];
    int b = blockIdx.z;
    int c0 = blockIdx.x * 32, s0 = blockIdx.y * 32;
    int tx = threadIdx.x, ty = threadIdx.y;
#pragma unroll
    for (int dy = 0; dy < 32; dy += 8) {
        size_t idx = ((size_t)b * 2048 + c0 + ty + dy) * 2048 + s0 + tx;
        tile[ty + dy][tx] = f2bf(bf2f(W[idx]) * bf2f(V[idx]));
    }
    __syncthreads();
#pragma unroll
    for (int dy = 0; dy < 32; dy += 8)
        out[((size_t)b * 2048 + s0 + ty + dy) * 2048 + c0 + tx] = tile[tx][ty + dy];
}

// ---------------------------------------------------------------------------
extern "C" void kernel_launch(void* const* d_in, const int* in_sizes, int n_in,
                              void* d_out, int out_size, void* d_ws, size_t ws_size,
                              hipStream_t stream) {
    const float* query = (const float*)d_in[0];
    const float* key   = (const float*)d_in[1];
    const float* value = (const float*)d_in[2];
    const float* Wq    = (const float*)d_in[3];
    const float* bq    = (const float*)d_in[4];
    const float* Wk    = (const float*)d_in[5];
    const float* bk    = (const float*)d_in[6];
    const float* Wv    = (const float*)d_in[7];
    const float* bv    = (const float*)d_in[8];
    const float* alpha = (const float*)d_in[9];
    const float* Wint  = (const float*)d_in[10];
    const float* bint  = (const float*)d_in[11];
    const float* Wfin  = (const float*)d_in[12];
    const float* bfin  = (const float*)d_in[13];
    const float* Wout  = (const float*)d_in[14];
    const float* bout  = (const float*)d_in[15];

    char* ws = (char*)d_ws;
    size_t off = 0;
    auto alloc = [&](size_t bytes) -> void* {
        void* p = ws + off;
        off += (bytes + 255) & ~(size_t)255;
        return p;
    };
    u16* Eq   = (u16*)alloc((size_t)2048 * 512 * 2);
    u16* Ek   = (u16*)alloc((size_t)2048 * 512 * 2);
    u16* Ev   = (u16*)alloc((size_t)2048 * 512 * 2);
    u16* Eint = (u16*)alloc((size_t)2048 * 2048 * 2);   // becomes Ecomb
    u16* Efin = (u16*)alloc((size_t)2048 * 2048 * 2);
    u16* Eout = (u16*)alloc((size_t)2048 * 2048 * 2);
    u16* EintT= (u16*)alloc((size_t)2048 * 2048 * 2);
    u16* T1T  = (u16*)alloc((size_t)2048 * 2048 * 2);
    u16* Qt   = (u16*)alloc((size_t)4 * 2048 * 2048 * 2);
    u16* Kt   = (u16*)alloc((size_t)4 * 2048 * 2048 * 2);
    u16* Vt   = (u16*)alloc((size_t)4 * 2048 * 2048 * 2);
    u16* attn = (u16*)alloc((size_t)8192 * 2048 * 2);
    float2* gws = (float2*)alloc(682 * 8);
    float*  pht = (float*)alloc(1025 * 4);
    float*  bv1 = (float*)alloc(2048 * 4);
    float*  bv2 = (float*)alloc(2048 * 4);
    u16* Ecomb = Eint;  // Eint (weights form) dead after EintT is built
    u16* Wt    = Qt;    // in-place: spectral reads its own channels fully
                        // before writing them; Eout/T1T stay live for combine2
    u16* Aq = attn;
    u16* Ak = attn + (size_t)8192 * 512;
    u16* Av = attn + (size_t)8192 * 1024;

    const int n8 = 8192 * 512 / 8;
    cvt3<<<dim3((n8 + 255) / 256, 3), 256, 0, stream>>>(query, key, value, Aq, n8);
    build_tabs<<<5, 256, 0, stream>>>(gws, pht);
    build_E3<9><<<dim3(4096, 3), 256, 0, stream>>>(Wq, Wk, Wv, Eq, Ek, Ev);
    build_E3<11><<<dim3(16384, 3), 256, 0, stream>>>(Wint, Wfin, Wout, Eint, Efin, Eout);

    dim3 gt1(64, 64, 1);
    transpose_k<<<gt1, dim3(32, 8), 0, stream>>>(Eint, EintT);

    // Layer 1: combine1 + all three projections in one grid
    fat_mm<<<3328, 256, 0, stream>>>(Aq, Eq, bq, Qt, Ak, Ek, bk, Kt,
                                     Av, Ev, bv, Vt, Efin, EintT, T1T);

    // combined bias: bv2 = (bint*Efin^T + bfin)*Eout^T + bout
    matvec_E<<<512, 256, 0, stream>>>(bint, Efin, bfin, bv1);
    matvec_E<<<512, 256, 0, stream>>>(bv1,  Eout, bout, bv2);

    // Layer 2: spectral weights (in-place over Qt) + combine2 co-scheduled
    fat_spec2<<<4352, 256, 0, stream>>>(Qt, Kt, Wt, alpha, gws, pht,
                                        Eout, T1T, Ecomb);

    // attn[(b,s)][c] = W[b][c][s] * V[b][c][s]
    dim3 gt(64, 64, 4);
    transpose_mul<<<gt, dim3(32, 8), 0, stream>>>(Wt, Vt, attn);

    // single fused trailing linear
    gemm2<2048, 1, 64><<<1024, 256, 0, stream>>>(attn, Ecomb, bv2, (float*)d_out);
}

// Round 15
// 377.992 us; speedup vs baseline: 1.1780x; 1.1780x over previous
//
#include <hip/hip_runtime.h>
#include <hip/hip_bf16.h>
#include <cstdint>

typedef unsigned short u16;
typedef u16  u16x8 __attribute__((ext_vector_type(8)));
typedef short s16x8 __attribute__((ext_vector_type(8)));
typedef float f32x4 __attribute__((ext_vector_type(4)));

#define PI_F 3.14159265358979323846f
#define PD(i) ((i) + 3 * ((i) >> 5))

static __device__ __forceinline__ u16 f2bf(float f) {
    union { float f; unsigned u; } v; v.f = f;
    unsigned r = v.u + 0x7fffu + ((v.u >> 16) & 1u);
    return (u16)(r >> 16);
}
static __device__ __forceinline__ float bf2f(u16 h) {
    union { unsigned u; float f; } v; v.u = ((unsigned)h) << 16;
    return v.f;
}

__device__ __forceinline__ void gl_lds16(const u16* g, u16* l) {
    __builtin_amdgcn_global_load_lds(
        (const __attribute__((address_space(1))) unsigned int*)g,
        (__attribute__((address_space(3))) unsigned int*)l, 16, 0, 0);
}

// ---------------------------------------------------------------------------
// Fused prep: cvt (f32->bf16, 3 tensors) + build_E (x6) + tables, one grid.
// Block ranges: [0,6144) cvt | [6144,18432) E<9>x3 | [18432,67584) E<11>x3 |
// [67584,67589) tables. All jobs independent.
// ---------------------------------------------------------------------------
__device__ __forceinline__ void cvt_body(int blk, const float* __restrict__ in,
                                         u16* __restrict__ o) {
    int i = blk * 256 + threadIdx.x;        // < 524288 exactly
    float4 a = ((const float4*)in)[2 * i];
    float4 b = ((const float4*)in)[2 * i + 1];
    u16x8 vv;
    vv[0] = f2bf(a.x); vv[1] = f2bf(a.y); vv[2] = f2bf(a.z); vv[3] = f2bf(a.w);
    vv[4] = f2bf(b.x); vv[5] = f2bf(b.y); vv[6] = f2bf(b.z); vv[7] = f2bf(b.w);
    ((u16x8*)o)[i] = vv;
}

template<int LOGK>
__device__ __forceinline__ void e3_body(int blk, const float* __restrict__ W,
                                        u16* __restrict__ E) {
    const int K = 1 << LOGK;
    int idx = blk * 256 + threadIdx.x;      // exact coverage
    int n = idx >> LOGK, k = idx & (K - 1);
    int o = n >> 2, c = n & 3, i = k >> 2, cp = k & 3;
    const int   qm[4][4] = {{0,1,2,3},{1,0,3,2},{2,3,0,1},{3,2,1,0}};
    const float qs[4][4] = {{1.f,-1.f,-1.f,-1.f},{1.f,1.f,1.f,-1.f},
                            {1.f,-1.f,1.f,1.f},{1.f,1.f,-1.f,1.f}};
    int in_q = K >> 2;
    float w = W[(size_t)qm[c][cp] * 512 * in_q + (size_t)o * in_q + i] * qs[c][cp];
    E[idx] = f2bf(w);
}

__device__ __forceinline__ void tabs_body(int blk, float2* __restrict__ gws,
                                          float* __restrict__ ph) {
    int i = blk * 256 + threadIdx.x;
    if (i < 682) {
        int off, lh;
        if (i < 2)        { off = 0;   lh = 1; }
        else if (i < 10)  { off = 2;   lh = 3; }
        else if (i < 42)  { off = 10;  lh = 5; }
        else if (i < 170) { off = 42;  lh = 7; }
        else              { off = 170; lh = 9; }
        int j = i - off;
        float a = (-PI_F) * (float)j / (float)(2 << lh);
        gws[i] = make_float2(cosf(a), sinf(a));
    }
    if (i <= 1024) {
        ph[i] = atanf(logf((float)i * (1.0f / 2048.0f) + 1e-6f));
    }
}

__global__ __launch_bounds__(256) void fat_prep(
        const float* __restrict__ query, const float* __restrict__ key,
        const float* __restrict__ value, u16* __restrict__ Acvt,
        const float* __restrict__ Wq, const float* __restrict__ Wk,
        const float* __restrict__ Wv, u16* __restrict__ Eq,
        u16* __restrict__ Ek, u16* __restrict__ Ev,
        const float* __restrict__ Wint, const float* __restrict__ Wfin,
        const float* __restrict__ Wout, u16* __restrict__ Eint,
        u16* __restrict__ Efin, u16* __restrict__ Eout,
        float2* __restrict__ gws, float* __restrict__ pht) {
    int b = blockIdx.x;
    if (b < 6144) {
        int ten = b >> 11, r = b & 2047;
        const float* in = (ten == 0) ? query : (ten == 1) ? key : value;
        cvt_body(r, in, Acvt + (size_t)ten * 8192 * 512);
    } else if (b < 18432) {
        int rb = b - 6144;
        int y = rb >> 12, r = rb & 4095;
        e3_body<9>(r, (y == 0) ? Wq : (y == 1) ? Wk : Wv,
                   (y == 0) ? Eq : (y == 1) ? Ek : Ev);
    } else if (b < 67584) {
        int rb = b - 18432;
        int y = rb >> 14, r = rb & 16383;
        e3_body<11>(r, (y == 0) ? Wint : (y == 1) ? Wfin : Wout,
                    (y == 0) ? Eint : (y == 1) ? Efin : Eout);
    } else {
        tabs_body(b - 67584, gws, pht);
    }
}

// ---------------------------------------------------------------------------
// Bias matvec: out[n] = sum_k v[k]*E[n][k] + badd[n]
// ---------------------------------------------------------------------------
__global__ __launch_bounds__(256) void matvec_E(const float* __restrict__ v,
                                                const u16* __restrict__ E,
                                                const float* __restrict__ badd,
                                                float* __restrict__ out) {
    int n    = (blockIdx.x * 256 + threadIdx.x) >> 6;
    int lane = threadIdx.x & 63;
    if (n >= 2048) return;
    const u16* row = E + (size_t)n * 2048;
    float s = 0.f;
    for (int j = lane; j < 2048; j += 64) s += v[j] * bf2f(row[j]);
#pragma unroll
    for (int o = 32; o; o >>= 1) s += __shfl_down(s, o, 64);
    if (lane == 0) out[n] = s + badd[n];
}

// ---------------------------------------------------------------------------
// bf16 MFMA GEMM body (m97 structure + XCD super-tiles). NBX=16, NBY=M/128.
// OUTMODE 0: bf16 [m][n]; 1: f32 [m][n]; 2: bf16 transposed [n][m]/[b][n][s]
// ---------------------------------------------------------------------------
template<int K, int OUTMODE, int NBY>
__device__ __forceinline__ void gemm_body(int bid, u16* As, u16* Bs,
                                          const u16* __restrict__ A,
                                          const u16* __restrict__ E,
                                          const float* __restrict__ bias,
                                          void* __restrict__ outp) {
    const int t    = threadIdx.x;
    const int lane = t & 63, wave = t >> 6;
    const int wr   = wave >> 1, wc = wave & 1;
    const int lr   = lane & 15, kg = lane >> 4;
    const int l7   = lr & 7;

    constexpr int SPX = (4 * (NBY / 4)) / 8;
    const int xcd = bid & 7, p = bid >> 3;
    const int st  = xcd * SPX + (p >> 4);
    const int w   = p & 15;
    const int bx  = (st & 3) * 4 + (w & 3);
    const int by  = (st >> 2) * 4 + (w >> 2);
    const int m0  = by * 128;
    const int n0  = bx * 128;

    f32x4 acc[4][4];
#pragma unroll
    for (int i = 0; i < 4; ++i)
#pragma unroll
        for (int j = 0; j < 4; ++j) acc[i][j] = (f32x4){0.f, 0.f, 0.f, 0.f};

    const int arow = wr * 64 + lr;
    const int brow = wc * 64 + lr;

    for (int k0 = 0; k0 < K; k0 += 64) {
#pragma unroll
        for (int c = 0; c < 4; ++c) {
            int idx = t + c * 256;
            int row = idx >> 3, sl = idx & 7;
            int gsl = sl ^ (row & 7);
            gl_lds16(A + (size_t)(m0 + row) * K + k0 + gsl * 8, &As[idx * 8]);
            gl_lds16(E + (size_t)(n0 + row) * K + k0 + gsl * 8, &Bs[idx * 8]);
        }
        __syncthreads();
#pragma unroll
        for (int ks = 0; ks < 2; ++ks) {
            const int slot = (ks * 4 + kg) ^ l7;
            s16x8 av[4], bv[4];
#pragma unroll
            for (int mi = 0; mi < 4; ++mi)
                av[mi] = *(const s16x8*)&As[(arow + mi * 16) * 64 + slot * 8];
#pragma unroll
            for (int ni = 0; ni < 4; ++ni)
                bv[ni] = *(const s16x8*)&Bs[(brow + ni * 16) * 64 + slot * 8];
#pragma unroll
            for (int mi = 0; mi < 4; ++mi)
#pragma unroll
                for (int ni = 0; ni < 4; ++ni)
                    acc[mi][ni] = __builtin_amdgcn_mfma_f32_16x16x32_bf16(
                        av[mi], bv[ni], acc[mi][ni], 0, 0, 0);
        }
        __syncthreads();
    }

#pragma unroll
    for (int ni = 0; ni < 4; ++ni) {
        int n = n0 + wc * 64 + ni * 16 + lr;
        float bvl = bias ? bias[n] : 0.0f;
#pragma unroll
        for (int mi = 0; mi < 4; ++mi) {
#pragma unroll
            for (int r = 0; r < 4; ++r) {
                int m = m0 + wr * 64 + mi * 16 + kg * 4 + r;
                float val = acc[mi][ni][r] + bvl;
                if constexpr (OUTMODE == 0) {
                    ((u16*)outp)[(size_t)m * 2048 + n] = f2bf(val);
                } else if constexpr (OUTMODE == 1) {
                    ((float*)outp)[(size_t)m * 2048 + n] = val;
                } else {
                    int b = m >> 11, s = m & 2047;
                    ((u16*)outp)[((size_t)b * 2048 + n) * 2048 + s] = f2bf(val);
                }
            }
        }
    }
}

template<int K, int OUTMODE, int NBY>
__global__ __launch_bounds__(256) void gemm2(const u16* __restrict__ A,
                                             const u16* __restrict__ E,
                                             const float* __restrict__ bias,
                                             void* __restrict__ outp) {
    __shared__ u16 As[128 * 64];
    __shared__ u16 Bs[128 * 64];
    gemm_body<K, OUTMODE, NBY>(blockIdx.x, As, Bs, A, E, bias, outp);
}

// Fat kernel 1: combine1 (Efin*EintT -> T1T, 256 blocks first) + projQ (1024)
__global__ __launch_bounds__(256) void gemm_fat1(const u16* __restrict__ Aq,
                                                 const u16* __restrict__ Eq,
                                                 const float* __restrict__ bq,
                                                 void* __restrict__ Qt,
                                                 const u16* __restrict__ Efin,
                                                 const u16* __restrict__ EintT,
                                                 void* __restrict__ T1T) {
    __shared__ u16 As[128 * 64];
    __shared__ u16 Bs[128 * 64];
    int bid = blockIdx.x;
    if (bid < 256)
        gemm_body<2048, 2, 16>(bid, As, Bs, Efin, EintT, nullptr, T1T);
    else
        gemm_body<512, 2, 64>(bid - 256, As, Bs, Aq, Eq, bq, Qt);
}

// Fat kernel 2: combine2 (Eout*T1T -> Ecomb, 256 blocks first) + projK (1024)
__global__ __launch_bounds__(256) void gemm_fat2(const u16* __restrict__ Ak,
                                                 const u16* __restrict__ Ek,
                                                 const float* __restrict__ bk,
                                                 void* __restrict__ Kt,
                                                 const u16* __restrict__ Eout,
                                                 const u16* __restrict__ T1T,
                                                 void* __restrict__ Ecomb) {
    __shared__ u16 As[128 * 64];
    __shared__ u16 Bs[128 * 64];
    int bid = blockIdx.x;
    if (bid < 256)
        gemm_body<2048, 0, 16>(bid, As, Bs, Eout, T1T, nullptr, Ecomb);
    else
        gemm_body<512, 2, 64>(bid - 256, As, Bs, Ak, Ek, bk, Kt);
}

// ---------------------------------------------------------------------------
// In-place FFT, bitrev input -> natural output. Radix-2 + radix-4 passes.
// ---------------------------------------------------------------------------
template<int LH, int OFF>
__device__ __forceinline__ void r4pass(float* re, float* im,
                                       const float2* __restrict__ wt, int t) {
    constexpr int h = 1 << LH;
    __syncthreads();
#pragma unroll
    for (int u = 0; u < 2; ++u) {
        int vidx = t + u * 256;
        int j = vidx & (h - 1);
        int i0 = ((vidx >> LH) << (LH + 2)) | j;
        float2 w2 = wt[OFF + j];
        float w1r = w2.x * w2.x - w2.y * w2.y;
        float w1i = 2.f * w2.x * w2.y;
        float w3r = w2.y, w3i = -w2.x;
        int p0 = PD(i0), p1 = PD(i0 + h), p2 = PD(i0 + 2 * h), p3 = PD(i0 + 3 * h);
        float ar = re[p0], ai = im[p0];
        float br = re[p1], bi = im[p1];
        float cr = re[p2], ci = im[p2];
        float dr = re[p3], di = im[p3];
        float tbr = w1r * br - w1i * bi, tbi = w1r * bi + w1i * br;
        float tdr = w1r * dr - w1i * di, tdi = w1r * di + w1i * dr;
        float a1r = ar + tbr, a1i = ai + tbi;
        float b1r = ar - tbr, b1i = ai - tbi;
        float c1r = cr + tdr, c1i = ci + tdi;
        float d1r = cr - tdr, d1i = ci - tdi;
        float tcr = w2.x * c1r - w2.y * c1i, tci = w2.x * c1i + w2.y * c1r;
        float ter = w3r * d1r - w3i * d1i, tei = w3r * d1i + w3i * d1r;
        re[p0] = a1r + tcr; im[p0] = a1i + tci;
        re[p2] = a1r - tcr; im[p2] = a1i - tci;
        re[p1] = b1r + ter; im[p1] = b1i + tei;
        re[p3] = b1r - ter; im[p3] = b1i - tei;
    }
}

__device__ void fft2048(float* re, float* im, const float2* __restrict__ wt, int t) {
    __syncthreads();
#pragma unroll
    for (int u = 0; u < 4; ++u) {
        int i0 = 2 * (t + u * 256);
        int p0 = PD(i0), p1 = p0 + 1;
        float ar = re[p0], ai = im[p0];
        float br = re[p1], bi = im[p1];
        re[p0] = ar + br; im[p0] = ai + bi;
        re[p1] = ar - br; im[p1] = ai - bi;
    }
    r4pass<1, 0>(re, im, wt, t);
    r4pass<3, 2>(re, im, wt, t);
    r4pass<5, 10>(re, im, wt, t);
    r4pass<7, 42>(re, im, wt, t);
    r4pass<9, 170>(re, im, wt, t);
    __syncthreads();
}

// ---------------------------------------------------------------------------
// Spectral body: 2 channels, packed FFTs; writes WEIGHTS to Wt (no V access).
// ---------------------------------------------------------------------------
__device__ void spectral_body(int sbid, float* zre, float* zim, float2* wt,
                              const u16* __restrict__ Qt,
                              const u16* __restrict__ Kt,
                              u16* __restrict__ Wt,
                              const float* __restrict__ alpha,
                              const float2* __restrict__ gws,
                              const float* __restrict__ gph) {
    const int t  = threadIdx.x;
    const int b  = sbid >> 10;
    const int cp = sbid & 1023;
    const int c0 = cp * 2;
    const size_t base0 = ((size_t)b * 2048 + c0) * 2048;
    const size_t base1 = base0 + 2048;

    for (int i = t; i < 682; i += 256) wt[i] = gws[i];

    float ph[4];
    float PH1r[4], PH1i[4], PH2r[4], PH2i[4];
    float ph24 = 0.f, PH24_1 = 0.f, PH24_2 = 0.f;

#pragma unroll
    for (int ch = 0; ch < 2; ++ch) {
        const size_t base = ch ? base1 : base0;
        const u16* Qp = Qt + base;
        const u16* Kp = Kt + base;
        __syncthreads();
#pragma unroll
        for (int u = 0; u < 8; ++u) {
            int s = t + u * 256;
            int r = __brev((unsigned)s) >> 21;
            zre[PD(r)] = bf2f(Qp[s]);
            zim[PD(r)] = bf2f(Kp[s]);
        }
        fft2048(zre, zim, wt, t);
        const float ac = alpha[c0 + ch];
#pragma unroll
        for (int u = 0; u < 4; ++u) {
            int k = t + u * 256;
            int m = (2048 - k) & 2047;
            float ar = zre[PD(k)], ai = zim[PD(k)];
            float br = zre[PD(m)], bi = zim[PD(m)];
            float qr = 0.5f * (ar + br), qi = 0.5f * (ai - bi);
            float kr = 0.5f * (ai + bi), ki = 0.5f * (br - ar);
            float cr = qr * kr + qi * ki;
            float ci = qi * kr - qr * ki;
            if (ch == 0) ph[u] = gph[min(k, 2048 - k)];
            float fr, fi;
            __sincosf(ph[u] * ac, &fi, &fr);
            float Pkr = cr * fr - ci * fi, Pki = cr * fi + ci * fr;
            float qr2 = 0.5f * (br + ar), qi2 = 0.5f * (bi - ai);
            float kr2 = 0.5f * (bi + ai), ki2 = 0.5f * (ar - br);
            float cr2 = qr2 * kr2 + qi2 * ki2;
            float ci2 = qi2 * kr2 - qr2 * ki2;
            float Pmr = cr2 * fr - ci2 * fi, Pmi = cr2 * fi + ci2 * fr;
            float hr = 0.5f * (Pkr + Pmr), hi = 0.5f * (Pki - Pmi);
            if (ch == 0) { PH1r[u] = hr; PH1i[u] = hi; }
            else         { PH2r[u] = hr; PH2i[u] = hi; }
        }
        if (t == 0) {
            float ar = zre[PD(1024)], ai = zim[PD(1024)];
            float cr = ar * ai;
            if (ch == 0) ph24 = gph[1024];
            float fr, fi;
            __sincosf(ph24 * ac, &fi, &fr);
            if (ch == 0) PH24_1 = cr * fr; else PH24_2 = cr * fr;
        }
    }

    __syncthreads();
#pragma unroll
    for (int u = 0; u < 4; ++u) {
        int k = t + u * 256;
        int m = (2048 - k) & 2047;
        int rk = __brev((unsigned)k) >> 21;
        int rm = __brev((unsigned)m) >> 21;
        zre[PD(rk)] = PH1r[u] - PH2i[u];
        zim[PD(rk)] = PH1i[u] + PH2r[u];
        zre[PD(rm)] = PH1r[u] + PH2i[u];
        zim[PD(rm)] = PH2r[u] - PH1i[u];
    }
    if (t == 0) {
        zre[PD(1)] = PH24_1;
        zim[PD(1)] = PH24_2;
    }
    fft2048(zre, zim, wt, t);

#pragma unroll
    for (int u = 0; u < 8; ++u) {
        int s = t + u * 256;
        int j = (2048 - s) & 2047;
        Wt[base0 + s] = f2bf(zre[PD(j)] * (1.0f / 2048.0f));
        Wt[base1 + s] = f2bf(zim[PD(j)] * (1.0f / 2048.0f));
    }
}

// Fat kernel: spectral (4096 blocks) + projV (1024 blocks), interleaved 4:1.
__global__ __launch_bounds__(256) void fat_specv(const u16* __restrict__ Qt,
                                                 const u16* __restrict__ Kt,
                                                 u16* __restrict__ Wt,
                                                 const float* __restrict__ alpha,
                                                 const float2* __restrict__ gws,
                                                 const float* __restrict__ gph,
                                                 const u16* __restrict__ Av,
                                                 const u16* __restrict__ Ev,
                                                 const float* __restrict__ bvb,
                                                 void* __restrict__ Vt) {
    __shared__ __align__(16) char smem[32768];
    int bid = blockIdx.x;
    if (bid % 5 == 4) {
        gemm_body<512, 2, 64>(bid / 5, (u16*)smem, (u16*)(smem + 16384),
                              Av, Ev, bvb, Vt);
    } else {
        int sbid = (bid / 5) * 4 + (bid % 5);
        spectral_body(sbid, (float*)smem, (float*)(smem + 8960),
                      (float2*)(smem + 17920), Qt, Kt, Wt, alpha, gws, gph);
    }
}

// ---------------------------------------------------------------------------
// Plain transpose (EintT) and fused multiply-transpose (attn = (W .* V)^T)
// ---------------------------------------------------------------------------
__global__ __launch_bounds__(256) void transpose_k(const u16* __restrict__ in,
                                                   u16* __restrict__ out) {
    __shared__ u16 tile[32][33];
    int b = blockIdx.z;
    int c0 = blockIdx.x * 32, s0 = blockIdx.y * 32;
    int tx = threadIdx.x, ty = threadIdx.y;
#pragma unroll
    for (int dy = 0; dy < 32; dy += 8)
        tile[ty + dy][tx] = in[((size_t)b * 2048 + c0 + ty + dy) * 2048 + s0 + tx];
    __syncthreads();
#pragma unroll
    for (int dy = 0; dy < 32; dy += 8)
        out[((size_t)b * 2048 + s0 + ty + dy) * 2048 + c0 + tx] = tile[tx][ty + dy];
}

__global__ __launch_bounds__(256) void transpose_mul(const u16* __restrict__ W,
                                                     const u16* __restrict__ V,
                                                     u16* __restrict__ out) {
    __shared__ u16 tile[32][33];
    int b = blockIdx.z;
    int c0 = blockIdx.x * 32, s0 = blockIdx.y * 32;
    int tx = threadIdx.x, ty = threadIdx.y;
#pragma unroll
    for (int dy = 0; dy < 32; dy += 8) {
        size_t idx = ((size_t)b * 2048 + c0 + ty + dy) * 2048 + s0 + tx;
        tile[ty + dy][tx] = f2bf(bf2f(W[idx]) * bf2f(V[idx]));
    }
    __syncthreads();
#pragma unroll
    for (int dy = 0; dy < 32; dy += 8)
        out[((size_t)b * 2048 + s0 + ty + dy) * 2048 + c0 + tx] = tile[tx][ty + dy];
}

// ---------------------------------------------------------------------------
extern "C" void kernel_launch(void* const* d_in, const int* in_sizes, int n_in,
                              void* d_out, int out_size, void* d_ws, size_t ws_size,
                              hipStream_t stream) {
    const float* query = (const float*)d_in[0];
    const float* key   = (const float*)d_in[1];
    const float* value = (const float*)d_in[2];
    const float* Wq    = (const float*)d_in[3];
    const float* bq    = (const float*)d_in[4];
    const float* Wk    = (const float*)d_in[5];
    const float* bk    = (const float*)d_in[6];
    const float* Wv    = (const float*)d_in[7];
    const float* bv    = (const float*)d_in[8];
    const float* alpha = (const float*)d_in[9];
    const float* Wint  = (const float*)d_in[10];
    const float* bint  = (const float*)d_in[11];
    const float* Wfin  = (const float*)d_in[12];
    const float* bfin  = (const float*)d_in[13];
    const float* Wout  = (const float*)d_in[14];
    const float* bout  = (const float*)d_in[15];

    char* ws = (char*)d_ws;
    size_t off = 0;
    auto alloc = [&](size_t bytes) -> void* {
        void* p = ws + off;
        off += (bytes + 255) & ~(size_t)255;
        return p;
    };
    u16* Eq   = (u16*)alloc((size_t)2048 * 512 * 2);
    u16* Ek   = (u16*)alloc((size_t)2048 * 512 * 2);
    u16* Ev   = (u16*)alloc((size_t)2048 * 512 * 2);
    u16* Eint = (u16*)alloc((size_t)2048 * 2048 * 2);   // becomes Ecomb
    u16* Efin = (u16*)alloc((size_t)2048 * 2048 * 2);   // Wt reuses Efin..T1T
    u16* Eout = (u16*)alloc((size_t)2048 * 2048 * 2);
    u16* EintT= (u16*)alloc((size_t)2048 * 2048 * 2);
    u16* T1T  = (u16*)alloc((size_t)2048 * 2048 * 2);
    u16* Qt   = (u16*)alloc((size_t)4 * 2048 * 2048 * 2);
    u16* Kt   = (u16*)alloc((size_t)4 * 2048 * 2048 * 2);
    u16* Vt   = (u16*)alloc((size_t)4 * 2048 * 2048 * 2);
    u16* attn = (u16*)alloc((size_t)8192 * 2048 * 2);
    float2* gws = (float2*)alloc(682 * 8);
    float*  pht = (float*)alloc(1025 * 4);
    float*  bv1 = (float*)alloc(2048 * 4);
    float*  bv2 = (float*)alloc(2048 * 4);
    u16* Ecomb = Eint;            // Eint dead (as weights) after EintT built
    u16* Wt    = Efin;            // Efin/Eout/EintT/T1T dead after matvecs
    u16* Aq = attn;
    u16* Ak = attn + (size_t)8192 * 512;
    u16* Av = attn + (size_t)8192 * 1024;

    // one fused prep dispatch: cvt x3, E<9> x3, E<11> x3, tables
    fat_prep<<<67589, 256, 0, stream>>>(query, key, value, Aq,
                                        Wq, Wk, Wv, Eq, Ek, Ev,
                                        Wint, Wfin, Wout, Eint, Efin, Eout,
                                        gws, pht);

    dim3 gt1(64, 64, 1);
    transpose_k<<<gt1, dim3(32, 8), 0, stream>>>(Eint, EintT);

    gemm_fat1<<<1280, 256, 0, stream>>>(Aq, Eq, bq, Qt, Efin, EintT, T1T);
    gemm_fat2<<<1280, 256, 0, stream>>>(Ak, Ek, bk, Kt, Eout, T1T, Ecomb);

    // combined bias (consumes Efin/Eout BEFORE Wt overwrites them)
    matvec_E<<<512, 256, 0, stream>>>(bint, Efin, bfin, bv1);
    matvec_E<<<512, 256, 0, stream>>>(bv1,  Eout, bout, bv2);

    // spectral weights + projV co-scheduled (independent block families)
    fat_specv<<<5120, 256, 0, stream>>>(Qt, Kt, Wt, alpha, gws, pht,
                                        Av, Ev, bv, Vt);

    // attn[(b,s)][c] = W[b][c][s] * V[b][c][s]
    dim3 gt(64, 64, 4);
    transpose_mul<<<gt, dim3(32, 8), 0, stream>>>(Wt, Vt, attn);

    // single fused trailing linear
    gemm2<2048, 1, 64><<<1024, 256, 0, stream>>>(attn, Ecomb, bv2, (float*)d_out);
}

// Round 17
// 373.362 us; speedup vs baseline: 1.1926x; 1.0124x over previous
//
#include <hip/hip_runtime.h>
#include <hip/hip_bf16.h>
#include <cstdint>

typedef unsigned short u16;
typedef u16  u16x8 __attribute__((ext_vector_type(8)));
typedef short s16x8 __attribute__((ext_vector_type(8)));
typedef float f32x4 __attribute__((ext_vector_type(4)));

#define PI_F 3.14159265358979323846f
#define PD(i) ((i) + 3 * ((i) >> 5))

static __device__ __forceinline__ u16 f2bf(float f) {
    union { float f; unsigned u; } v; v.f = f;
    unsigned r = v.u + 0x7fffu + ((v.u >> 16) & 1u);
    return (u16)(r >> 16);
}
static __device__ __forceinline__ float bf2f(u16 h) {
    union { unsigned u; float f; } v; v.u = ((unsigned)h) << 16;
    return v.f;
}

__device__ __forceinline__ void gl_lds16(const u16* g, u16* l) {
    __builtin_amdgcn_global_load_lds(
        (const __attribute__((address_space(1))) unsigned int*)g,
        (__attribute__((address_space(3))) unsigned int*)l, 16, 0, 0);
}

// ---------------------------------------------------------------------------
// Fused prep: cvt (f32->bf16, 3 tensors) + build_E (x6) + tables, one grid.
// ---------------------------------------------------------------------------
__device__ __forceinline__ void cvt_body(int blk, const float* __restrict__ in,
                                         u16* __restrict__ o) {
    int i = blk * 256 + threadIdx.x;
    float4 a = ((const float4*)in)[2 * i];
    float4 b = ((const float4*)in)[2 * i + 1];
    u16x8 vv;
    vv[0] = f2bf(a.x); vv[1] = f2bf(a.y); vv[2] = f2bf(a.z); vv[3] = f2bf(a.w);
    vv[4] = f2bf(b.x); vv[5] = f2bf(b.y); vv[6] = f2bf(b.z); vv[7] = f2bf(b.w);
    ((u16x8*)o)[i] = vv;
}

template<int LOGK>
__device__ __forceinline__ void e3_body(int blk, const float* __restrict__ W,
                                        u16* __restrict__ E) {
    const int K = 1 << LOGK;
    int idx = blk * 256 + threadIdx.x;
    int n = idx >> LOGK, k = idx & (K - 1);
    int o = n >> 2, c = n & 3, i = k >> 2, cp = k & 3;
    const int   qm[4][4] = {{0,1,2,3},{1,0,3,2},{2,3,0,1},{3,2,1,0}};
    const float qs[4][4] = {{1.f,-1.f,-1.f,-1.f},{1.f,1.f,1.f,-1.f},
                            {1.f,-1.f,1.f,1.f},{1.f,1.f,-1.f,1.f}};
    int in_q = K >> 2;
    float w = W[(size_t)qm[c][cp] * 512 * in_q + (size_t)o * in_q + i] * qs[c][cp];
    E[idx] = f2bf(w);
}

// r8 twiddle tables: h=4 @0 (4) | h=32 @4 (32) | h=256 @36 (256) -> 292.
__device__ __forceinline__ void tabs_body(int blk, float2* __restrict__ gws,
                                          float* __restrict__ ph) {
    int i = blk * 256 + threadIdx.x;
    if (i < 292) {
        int off, denom;
        if (i < 4)       { off = 0;  denom = 16;   }
        else if (i < 36) { off = 4;  denom = 128;  }
        else             { off = 36; denom = 1024; }
        float a = (-PI_F) * (float)(i - off) / (float)denom;
        gws[i] = make_float2(cosf(a), sinf(a));
    }
    if (i <= 1024) {
        ph[i] = atanf(logf((float)i * (1.0f / 2048.0f) + 1e-6f));
    }
}

__global__ __launch_bounds__(256) void fat_prep(
        const float* __restrict__ query, const float* __restrict__ key,
        const float* __restrict__ value, u16* __restrict__ Acvt,
        const float* __restrict__ Wq, const float* __restrict__ Wk,
        const float* __restrict__ Wv, u16* __restrict__ Eq,
        u16* __restrict__ Ek, u16* __restrict__ Ev,
        const float* __restrict__ Wint, const float* __restrict__ Wfin,
        const float* __restrict__ Wout, u16* __restrict__ Eint,
        u16* __restrict__ Efin, u16* __restrict__ Eout,
        float2* __restrict__ gws, float* __restrict__ pht) {
    int b = blockIdx.x;
    if (b < 6144) {
        int ten = b >> 11, r = b & 2047;
        const float* in = (ten == 0) ? query : (ten == 1) ? key : value;
        cvt_body(r, in, Acvt + (size_t)ten * 8192 * 512);
    } else if (b < 18432) {
        int rb = b - 6144;
        int y = rb >> 12, r = rb & 4095;
        e3_body<9>(r, (y == 0) ? Wq : (y == 1) ? Wk : Wv,
                   (y == 0) ? Eq : (y == 1) ? Ek : Ev);
    } else if (b < 67584) {
        int rb = b - 18432;
        int y = rb >> 14, r = rb & 16383;
        e3_body<11>(r, (y == 0) ? Wint : (y == 1) ? Wfin : Wout,
                    (y == 0) ? Eint : (y == 1) ? Efin : Eout);
    } else {
        tabs_body(b - 67584, gws, pht);
    }
}

// ---------------------------------------------------------------------------
// Bias matvec: out[n] = sum_k v[k]*E[n][k] + badd[n]
// ---------------------------------------------------------------------------
__global__ __launch_bounds__(256) void matvec_E(const float* __restrict__ v,
                                                const u16* __restrict__ E,
                                                const float* __restrict__ badd,
                                                float* __restrict__ out) {
    int n    = (blockIdx.x * 256 + threadIdx.x) >> 6;
    int lane = threadIdx.x & 63;
    if (n >= 2048) return;
    const u16* row = E + (size_t)n * 2048;
    float s = 0.f;
    for (int j = lane; j < 2048; j += 64) s += v[j] * bf2f(row[j]);
#pragma unroll
    for (int o = 32; o; o >>= 1) s += __shfl_down(s, o, 64);
    if (lane == 0) out[n] = s + badd[n];
}

// ---------------------------------------------------------------------------
// bf16 MFMA GEMM body (m97 structure + XCD super-tiles). NBX=16, NBY=M/128.
// OUTMODE 0: bf16 [m][n]; 1: f32 [m][n]; 2: bf16 transposed [n][m]/[b][n][s]
// ---------------------------------------------------------------------------
template<int K, int OUTMODE, int NBY>
__device__ __forceinline__ void gemm_body(int bid, u16* As, u16* Bs,
                                          const u16* __restrict__ A,
                                          const u16* __restrict__ E,
                                          const float* __restrict__ bias,
                                          void* __restrict__ outp) {
    const int t    = threadIdx.x;
    const int lane = t & 63, wave = t >> 6;
    const int wr   = wave >> 1, wc = wave & 1;
    const int lr   = lane & 15, kg = lane >> 4;
    const int l7   = lr & 7;

    constexpr int SPX = (4 * (NBY / 4)) / 8;
    const int xcd = bid & 7, p = bid >> 3;
    const int st  = xcd * SPX + (p >> 4);
    const int w   = p & 15;
    const int bx  = (st & 3) * 4 + (w & 3);
    const int by  = (st >> 2) * 4 + (w >> 2);
    const int m0  = by * 128;
    const int n0  = bx * 128;

    f32x4 acc[4][4];
#pragma unroll
    for (int i = 0; i < 4; ++i)
#pragma unroll
        for (int j = 0; j < 4; ++j) acc[i][j] = (f32x4){0.f, 0.f, 0.f, 0.f};

    const int arow = wr * 64 + lr;
    const int brow = wc * 64 + lr;

    for (int k0 = 0; k0 < K; k0 += 64) {
#pragma unroll
        for (int c = 0; c < 4; ++c) {
            int idx = t + c * 256;
            int row = idx >> 3, sl = idx & 7;
            int gsl = sl ^ (row & 7);
            gl_lds16(A + (size_t)(m0 + row) * K + k0 + gsl * 8, &As[idx * 8]);
            gl_lds16(E + (size_t)(n0 + row) * K + k0 + gsl * 8, &Bs[idx * 8]);
        }
        __syncthreads();
#pragma unroll
        for (int ks = 0; ks < 2; ++ks) {
            const int slot = (ks * 4 + kg) ^ l7;
            s16x8 av[4], bv[4];
#pragma unroll
            for (int mi = 0; mi < 4; ++mi)
                av[mi] = *(const s16x8*)&As[(arow + mi * 16) * 64 + slot * 8];
#pragma unroll
            for (int ni = 0; ni < 4; ++ni)
                bv[ni] = *(const s16x8*)&Bs[(brow + ni * 16) * 64 + slot * 8];
#pragma unroll
            for (int mi = 0; mi < 4; ++mi)
#pragma unroll
                for (int ni = 0; ni < 4; ++ni)
                    acc[mi][ni] = __builtin_amdgcn_mfma_f32_16x16x32_bf16(
                        av[mi], bv[ni], acc[mi][ni], 0, 0, 0);
        }
        __syncthreads();
    }

#pragma unroll
    for (int ni = 0; ni < 4; ++ni) {
        int n = n0 + wc * 64 + ni * 16 + lr;
        float bvl = bias ? bias[n] : 0.0f;
#pragma unroll
        for (int mi = 0; mi < 4; ++mi) {
#pragma unroll
            for (int r = 0; r < 4; ++r) {
                int m = m0 + wr * 64 + mi * 16 + kg * 4 + r;
                float val = acc[mi][ni][r] + bvl;
                if constexpr (OUTMODE == 0) {
                    ((u16*)outp)[(size_t)m * 2048 + n] = f2bf(val);
                } else if constexpr (OUTMODE == 1) {
                    ((float*)outp)[(size_t)m * 2048 + n] = val;
                } else {
                    int b = m >> 11, s = m & 2047;
                    ((u16*)outp)[((size_t)b * 2048 + n) * 2048 + s] = f2bf(val);
                }
            }
        }
    }
}

template<int K, int OUTMODE, int NBY>
__global__ __launch_bounds__(256) void gemm2(const u16* __restrict__ A,
                                             const u16* __restrict__ E,
                                             const float* __restrict__ bias,
                                             void* __restrict__ outp) {
    __shared__ u16 As[128 * 64];
    __shared__ u16 Bs[128 * 64];
    gemm_body<K, OUTMODE, NBY>(blockIdx.x, As, Bs, A, E, bias, outp);
}

// Fat kernel 1: combine1 (Efin*EintT -> T1T, 256 blocks first) + projQ (1024)
__global__ __launch_bounds__(256) void gemm_fat1(const u16* __restrict__ Aq,
                                                 const u16* __restrict__ Eq,
                                                 const float* __restrict__ bq,
                                                 void* __restrict__ Qt,
                                                 const u16* __restrict__ Efin,
                                                 const u16* __restrict__ EintT,
                                                 void* __restrict__ T1T) {
    __shared__ u16 As[128 * 64];
    __shared__ u16 Bs[128 * 64];
    int bid = blockIdx.x;
    if (bid < 256)
        gemm_body<2048, 2, 16>(bid, As, Bs, Efin, EintT, nullptr, T1T);
    else
        gemm_body<512, 2, 64>(bid - 256, As, Bs, Aq, Eq, bq, Qt);
}

// Fat kernel 2: combine2 (Eout*T1T -> Ecomb, 256 blocks first) + projK (1024)
__global__ __launch_bounds__(256) void gemm_fat2(const u16* __restrict__ Ak,
                                                 const u16* __restrict__ Ek,
                                                 const float* __restrict__ bk,
                                                 void* __restrict__ Kt,
                                                 const u16* __restrict__ Eout,
                                                 const u16* __restrict__ T1T,
                                                 void* __restrict__ Ecomb) {
    __shared__ u16 As[128 * 64];
    __shared__ u16 Bs[128 * 64];
    int bid = blockIdx.x;
    if (bid < 256)
        gemm_body<2048, 0, 16>(bid, As, Bs, Eout, T1T, nullptr, Ecomb);
    else
        gemm_body<512, 2, 64>(bid - 256, As, Bs, Ak, Ek, bk, Kt);
}

// ---------------------------------------------------------------------------
// In-place FFT, bitrev input -> natural output.
// Twiddle-free radix-4 (stages 0-1) + radix-8 passes (stages 2-4, 5-7, 8-10).
// ---------------------------------------------------------------------------
template<int LH, int OFF>
__device__ __forceinline__ void r8pass(float* re, float* im,
                                       const float2* __restrict__ wt, int t) {
    constexpr int h = 1 << LH;
    __syncthreads();
    const int j  = t & (h - 1);
    const int i0 = ((t >> LH) << (LH + 3)) | j;
    const float2 w = wt[OFF + j];               // t3 = cis(-pi*j/(4h))
    const float t2r = w.x * w.x - w.y * w.y;    // t2 = t3^2
    const float t2i = 2.f * w.x * w.y;
    const float t1r = t2r * t2r - t2i * t2i;    // t1 = t3^4
    const float t1i = 2.f * t2r * t2i;
    const float S = 0.70710678118654752f;
    const float Ac = S * (w.x + w.y);           // t3*cis(-pi/4) = (Ac, Bc)
    const float Bc = S * (w.y - w.x);           // t3*cis(-3pi/4) = (Bc, -Ac)

    float xr[8], xi[8];
    int p[8];
#pragma unroll
    for (int k = 0; k < 8; ++k) {
        p[k] = PD(i0 + k * h);
        xr[k] = re[p[k]]; xi[k] = im[p[k]];
    }
#pragma unroll
    for (int kp = 0; kp < 8; kp += 2) {
        float tr = t1r * xr[kp + 1] - t1i * xi[kp + 1];
        float ti = t1r * xi[kp + 1] + t1i * xr[kp + 1];
        float ar = xr[kp], ai = xi[kp];
        xr[kp] = ar + tr;     xi[kp] = ai + ti;
        xr[kp + 1] = ar - tr; xi[kp + 1] = ai - ti;
    }
#pragma unroll
    for (int q = 0; q < 2; ++q) {
        int b0 = q * 4;
        {
            float tr = t2r * xr[b0 + 2] - t2i * xi[b0 + 2];
            float ti = t2r * xi[b0 + 2] + t2i * xr[b0 + 2];
            float ar = xr[b0], ai = xi[b0];
            xr[b0] = ar + tr;     xi[b0] = ai + ti;
            xr[b0 + 2] = ar - tr; xi[b0 + 2] = ai - ti;
        }
        {
            float tr = t2i * xr[b0 + 3] + t2r * xi[b0 + 3];
            float ti = t2i * xi[b0 + 3] - t2r * xr[b0 + 3];
            float ar = xr[b0 + 1], ai = xi[b0 + 1];
            xr[b0 + 1] = ar + tr; xi[b0 + 1] = ai + ti;
            xr[b0 + 3] = ar - tr; xi[b0 + 3] = ai - ti;
        }
    }
    {
        float tr = w.x * xr[4] - w.y * xi[4];
        float ti = w.x * xi[4] + w.y * xr[4];
        float ar = xr[0], ai = xi[0];
        xr[0] = ar + tr; xi[0] = ai + ti;
        xr[4] = ar - tr; xi[4] = ai - ti;
    }
    {
        float tr = Ac * xr[5] - Bc * xi[5];
        float ti = Ac * xi[5] + Bc * xr[5];
        float ar = xr[1], ai = xi[1];
        xr[1] = ar + tr; xi[1] = ai + ti;
        xr[5] = ar - tr; xi[5] = ai - ti;
    }
    {
        float tr = w.y * xr[6] + w.x * xi[6];
        float ti = w.y * xi[6] - w.x * xr[6];
        float ar = xr[2], ai = xi[2];
        xr[2] = ar + tr; xi[2] = ai + ti;
        xr[6] = ar - tr; xi[6] = ai - ti;
    }
    {
        float tr = Bc * xr[7] + Ac * xi[7];
        float ti = Bc * xi[7] - Ac * xr[7];
        float ar = xr[3], ai = xi[3];
        xr[3] = ar + tr; xi[3] = ai + ti;
        xr[7] = ar - tr; xi[7] = ai - ti;
    }
#pragma unroll
    for (int k = 0; k < 8; ++k) { re[p[k]] = xr[k]; im[p[k]] = xi[k]; }
}

__device__ void fft2048(float* re, float* im, const float2* __restrict__ wt, int t) {
    __syncthreads();   // input scatter complete
#pragma unroll
    for (int u = 0; u < 2; ++u) {
        int i0 = (t + u * 256) << 2;
        int p0 = PD(i0);
        float x0r = re[p0],     x0i = im[p0];
        float x1r = re[p0 + 1], x1i = im[p0 + 1];
        float x2r = re[p0 + 2], x2i = im[p0 + 2];
        float x3r = re[p0 + 3], x3i = im[p0 + 3];
        float ar = x0r + x1r, ai = x0i + x1i;
        float br = x0r - x1r, bi = x0i - x1i;
        float cr = x2r + x3r, ci = x2i + x3i;
        float dr = x2r - x3r, di = x2i - x3i;
        re[p0]     = ar + cr; im[p0]     = ai + ci;
        re[p0 + 2] = ar - cr; im[p0 + 2] = ai - ci;
        re[p0 + 1] = br + di; im[p0 + 1] = bi - dr;
        re[p0 + 3] = br - di; im[p0 + 3] = bi + dr;
    }
    r8pass<2, 0>(re, im, wt, t);
    r8pass<5, 4>(re, im, wt, t);
    r8pass<8, 36>(re, im, wt, t);
    __syncthreads();
}

// ---------------------------------------------------------------------------
// Spectral body: 2 channels, packed FFTs; writes WEIGHTS to Wt (no V access).
// ---------------------------------------------------------------------------
__device__ void spectral_body(int sbid, float* zre, float* zim, float2* wt,
                              const u16* __restrict__ Qt,
                              const u16* __restrict__ Kt,
                              u16* __restrict__ Wt,
                              const float* __restrict__ alpha,
                              const float2* __restrict__ gws,
                              const float* __restrict__ gph) {
    const int t  = threadIdx.x;
    const int b  = sbid >> 10;
    const int cp = sbid & 1023;
    const int c0 = cp * 2;
    const size_t base0 = ((size_t)b * 2048 + c0) * 2048;
    const size_t base1 = base0 + 2048;

    for (int i = t; i < 292; i += 256) wt[i] = gws[i];   // FIX: strided (292>256)

    float ph[4];
    float PH1r[4], PH1i[4], PH2r[4], PH2i[4];
    float ph24 = 0.f, PH24_1 = 0.f, PH24_2 = 0.f;

#pragma unroll
    for (int ch = 0; ch < 2; ++ch) {
        const size_t base = ch ? base1 : base0;
        const u16* Qp = Qt + base;
        const u16* Kp = Kt + base;
        __syncthreads();
#pragma unroll
        for (int u = 0; u < 8; ++u) {
            int s = t + u * 256;
            int r = __brev((unsigned)s) >> 21;
            zre[PD(r)] = bf2f(Qp[s]);
            zim[PD(r)] = bf2f(Kp[s]);
        }
        fft2048(zre, zim, wt, t);
        const float ac = alpha[c0 + ch];
#pragma unroll
        for (int u = 0; u < 4; ++u) {
            int k = t + u * 256;
            int m = (2048 - k) & 2047;
            float ar = zre[PD(k)], ai = zim[PD(k)];
            float br = zre[PD(m)], bi = zim[PD(m)];
            float qr = 0.5f * (ar + br), qi = 0.5f * (ai - bi);
            float kr = 0.5f * (ai + bi), ki = 0.5f * (br - ar);
            float cr = qr * kr + qi * ki;
            float ci = qi * kr - qr * ki;
            if (ch == 0) ph[u] = gph[min(k, 2048 - k)];
            float fr, fi;
            __sincosf(ph[u] * ac, &fi, &fr);
            float Pkr = cr * fr - ci * fi, Pki = cr * fi + ci * fr;
            float qr2 = 0.5f * (br + ar), qi2 = 0.5f * (bi - ai);
            float kr2 = 0.5f * (bi + ai), ki2 = 0.5f * (ar - br);
            float cr2 = qr2 * kr2 + qi2 * ki2;
            float ci2 = qi2 * kr2 - qr2 * ki2;
            float Pmr = cr2 * fr - ci2 * fi, Pmi = cr2 * fi + ci2 * fr;
            float hr = 0.5f * (Pkr + Pmr), hi = 0.5f * (Pki - Pmi);
            if (ch == 0) { PH1r[u] = hr; PH1i[u] = hi; }
            else         { PH2r[u] = hr; PH2i[u] = hi; }
        }
        if (t == 0) {
            float ar = zre[PD(1024)], ai = zim[PD(1024)];
            float cr = ar * ai;
            if (ch == 0) ph24 = gph[1024];
            float fr, fi;
            __sincosf(ph24 * ac, &fi, &fr);
            if (ch == 0) PH24_1 = cr * fr; else PH24_2 = cr * fr;
        }
    }

    __syncthreads();
#pragma unroll
    for (int u = 0; u < 4; ++u) {
        int k = t + u * 256;
        int m = (2048 - k) & 2047;
        int rk = __brev((unsigned)k) >> 21;
        int rm = __brev((unsigned)m) >> 21;
        zre[PD(rk)] = PH1r[u] - PH2i[u];
        zim[PD(rk)] = PH1i[u] + PH2r[u];
        zre[PD(rm)] = PH1r[u] + PH2i[u];
        zim[PD(rm)] = PH2r[u] - PH1i[u];
    }
    if (t == 0) {
        zre[PD(1)] = PH24_1;
        zim[PD(1)] = PH24_2;
    }
    fft2048(zre, zim, wt, t);

#pragma unroll
    for (int u = 0; u < 8; ++u) {
        int s = t + u * 256;
        int j = (2048 - s) & 2047;
        Wt[base0 + s] = f2bf(zre[PD(j)] * (1.0f / 2048.0f));
        Wt[base1 + s] = f2bf(zim[PD(j)] * (1.0f / 2048.0f));
    }
}

// Fat kernel: spectral (4096 blocks) + projV (1024 blocks), interleaved 4:1.
__global__ __launch_bounds__(256) void fat_specv(const u16* __restrict__ Qt,
                                                 const u16* __restrict__ Kt,
                                                 u16* __restrict__ Wt,
                                                 const float* __restrict__ alpha,
                                                 const float2* __restrict__ gws,
                                                 const float* __restrict__ gph,
                                                 const u16* __restrict__ Av,
                                                 const u16* __restrict__ Ev,
                                                 const float* __restrict__ bvb,
                                                 void* __restrict__ Vt) {
    __shared__ __align__(16) char smem[32768];
    int bid = blockIdx.x;
    if (bid % 5 == 4) {
        gemm_body<512, 2, 64>(bid / 5, (u16*)smem, (u16*)(smem + 16384),
                              Av, Ev, bvb, Vt);
    } else {
        int sbid = (bid / 5) * 4 + (bid % 5);
        spectral_body(sbid, (float*)smem, (float*)(smem + 8960),
                      (float2*)(smem + 17920), Qt, Kt, Wt, alpha, gws, gph);
    }
}

// ---------------------------------------------------------------------------
// Plain transpose (EintT) and fused multiply-transpose (attn = (W .* V)^T)
// ---------------------------------------------------------------------------
__global__ __launch_bounds__(256) void transpose_k(const u16* __restrict__ in,
                                                   u16* __restrict__ out) {
    __shared__ u16 tile[32][33];
    int b = blockIdx.z;
    int c0 = blockIdx.x * 32, s0 = blockIdx.y * 32;
    int tx = threadIdx.x, ty = threadIdx.y;
#pragma unroll
    for (int dy = 0; dy < 32; dy += 8)
        tile[ty + dy][tx] = in[((size_t)b * 2048 + c0 + ty + dy) * 2048 + s0 + tx];
    __syncthreads();
#pragma unroll
    for (int dy = 0; dy < 32; dy += 8)
        out[((size_t)b * 2048 + s0 + ty + dy) * 2048 + c0 + tx] = tile[tx][ty + dy];
}

__global__ __launch_bounds__(256) void transpose_mul(const u16* __restrict__ W,
                                                     const u16* __restrict__ V,
                                                     u16* __restrict__ out) {
    __shared__ u16 tile[32][33];
    int b = blockIdx.z;
    int c0 = blockIdx.x * 32, s0 = blockIdx.y * 32;
    int tx = threadIdx.x, ty = threadIdx.y;
#pragma unroll
    for (int dy = 0; dy < 32; dy += 8) {
        size_t idx = ((size_t)b * 2048 + c0 + ty + dy) * 2048 + s0 + tx;
        tile[ty + dy][tx] = f2bf(bf2f(W[idx]) * bf2f(V[idx]));
    }
    __syncthreads();
#pragma unroll
    for (int dy = 0; dy < 32; dy += 8)
        out[((size_t)b * 2048 + s0 + ty + dy) * 2048 + c0 + tx] = tile[tx][ty + dy];
}

// ---------------------------------------------------------------------------
extern "C" void kernel_launch(void* const* d_in, const int* in_sizes, int n_in,
                              void* d_out, int out_size, void* d_ws, size_t ws_size,
                              hipStream_t stream) {
    const float* query = (const float*)d_in[0];
    const float* key   = (const float*)d_in[1];
    const float* value = (const float*)d_in[2];
    const float* Wq    = (const float*)d_in[3];
    const float* bq    = (const float*)d_in[4];
    const float* Wk    = (const float*)d_in[5];
    const float* bk    = (const float*)d_in[6];
    const float* Wv    = (const float*)d_in[7];
    const float* bv    = (const float*)d_in[8];
    const float* alpha = (const float*)d_in[9];
    const float* Wint  = (const float*)d_in[10];
    const float* bint  = (const float*)d_in[11];
    const float* Wfin  = (const float*)d_in[12];
    const float* bfin  = (const float*)d_in[13];
    const float* Wout  = (const float*)d_in[14];
    const float* bout  = (const float*)d_in[15];

    char* ws = (char*)d_ws;
    size_t off = 0;
    auto alloc = [&](size_t bytes) -> void* {
        void* p = ws + off;
        off += (bytes + 255) & ~(size_t)255;
        return p;
    };
    u16* Eq   = (u16*)alloc((size_t)2048 * 512 * 2);
    u16* Ek   = (u16*)alloc((size_t)2048 * 512 * 2);
    u16* Ev   = (u16*)alloc((size_t)2048 * 512 * 2);
    u16* Eint = (u16*)alloc((size_t)2048 * 2048 * 2);   // becomes Ecomb
    u16* Efin = (u16*)alloc((size_t)2048 * 2048 * 2);   // Wt reuses Efin..T1T
    u16* Eout = (u16*)alloc((size_t)2048 * 2048 * 2);
    u16* EintT= (u16*)alloc((size_t)2048 * 2048 * 2);
    u16* T1T  = (u16*)alloc((size_t)2048 * 2048 * 2);
    u16* Qt   = (u16*)alloc((size_t)4 * 2048 * 2048 * 2);
    u16* Kt   = (u16*)alloc((size_t)4 * 2048 * 2048 * 2);
    u16* Vt   = (u16*)alloc((size_t)4 * 2048 * 2048 * 2);
    u16* attn = (u16*)alloc((size_t)8192 * 2048 * 2);
    float2* gws = (float2*)alloc(292 * 8);
    float*  pht = (float*)alloc(1025 * 4);
    float*  bv1 = (float*)alloc(2048 * 4);
    float*  bv2 = (float*)alloc(2048 * 4);
    u16* Ecomb = Eint;            // Eint dead (as weights) after EintT built
    u16* Wt    = Efin;            // Efin/Eout/EintT/T1T dead after matvecs
    u16* Aq = attn;
    u16* Ak = attn + (size_t)8192 * 512;
    u16* Av = attn + (size_t)8192 * 1024;

    // one fused prep dispatch: cvt x3, E<9> x3, E<11> x3, tables
    fat_prep<<<67589, 256, 0, stream>>>(query, key, value, Aq,
                                        Wq, Wk, Wv, Eq, Ek, Ev,
                                        Wint, Wfin, Wout, Eint, Efin, Eout,
                                        gws, pht);

    dim3 gt1(64, 64, 1);
    transpose_k<<<gt1, dim3(32, 8), 0, stream>>>(Eint, EintT);

    gemm_fat1<<<1280, 256, 0, stream>>>(Aq, Eq, bq, Qt, Efin, EintT, T1T);
    gemm_fat2<<<1280, 256, 0, stream>>>(Ak, Ek, bk, Kt, Eout, T1T, Ecomb);

    // combined bias (consumes Efin/Eout BEFORE Wt overwrites them)
    matvec_E<<<512, 256, 0, stream>>>(bint, Efin, bfin, bv1);
    matvec_E<<<512, 256, 0, stream>>>(bv1,  Eout, bout, bv2);

    // spectral weights + projV co-scheduled (independent block families)
    fat_specv<<<5120, 256, 0, stream>>>(Qt, Kt, Wt, alpha, gws, pht,
                                        Av, Ev, bv, Vt);

    // attn[(b,s)][c] = W[b][c][s] * V[b][c][s]
    dim3 gt(64, 64, 4);
    transpose_mul<<<gt, dim3(32, 8), 0, stream>>>(Wt, Vt, attn);

    // single fused trailing linear
    gemm2<2048, 1, 64><<<1024, 256, 0, stream>>>(attn, Ecomb, bv2, (float*)d_out);
}

// Round 18
// 361.475 us; speedup vs baseline: 1.2318x; 1.0329x over previous
//
#include <hip/hip_runtime.h>
#include <hip/hip_bf16.h>
#include <cstdint>

typedef unsigned short u16;
typedef u16  u16x8 __attribute__((ext_vector_type(8)));
typedef short s16x8 __attribute__((ext_vector_type(8)));
typedef float f32x4 __attribute__((ext_vector_type(4)));

#define PI_F 3.14159265358979323846f
#define PD(i) ((i) + 3 * ((i) >> 5))

static __device__ __forceinline__ u16 f2bf(float f) {
    union { float f; unsigned u; } v; v.f = f;
    unsigned r = v.u + 0x7fffu + ((v.u >> 16) & 1u);
    return (u16)(r >> 16);
}
static __device__ __forceinline__ float bf2f(u16 h) {
    union { unsigned u; float f; } v; v.u = ((unsigned)h) << 16;
    return v.f;
}

__device__ __forceinline__ void gl_lds16(const u16* g, u16* l) {
    __builtin_amdgcn_global_load_lds(
        (const __attribute__((address_space(1))) unsigned int*)g,
        (__attribute__((address_space(3))) unsigned int*)l, 16, 0, 0);
}

// ---------------------------------------------------------------------------
// Fused prep: cvt (f32->bf16, 3 tensors) + build_E (x6) + tables, one grid.
// ---------------------------------------------------------------------------
__device__ __forceinline__ void cvt_body(int blk, const float* __restrict__ in,
                                         u16* __restrict__ o) {
    int i = blk * 256 + threadIdx.x;
    float4 a = ((const float4*)in)[2 * i];
    float4 b = ((const float4*)in)[2 * i + 1];
    u16x8 vv;
    vv[0] = f2bf(a.x); vv[1] = f2bf(a.y); vv[2] = f2bf(a.z); vv[3] = f2bf(a.w);
    vv[4] = f2bf(b.x); vv[5] = f2bf(b.y); vv[6] = f2bf(b.z); vv[7] = f2bf(b.w);
    ((u16x8*)o)[i] = vv;
}

template<int LOGK>
__device__ __forceinline__ void e3_body(int blk, const float* __restrict__ W,
                                        u16* __restrict__ E) {
    const int K = 1 << LOGK;
    int idx = blk * 256 + threadIdx.x;
    int n = idx >> LOGK, k = idx & (K - 1);
    int o = n >> 2, c = n & 3, i = k >> 2, cp = k & 3;
    const int   qm[4][4] = {{0,1,2,3},{1,0,3,2},{2,3,0,1},{3,2,1,0}};
    const float qs[4][4] = {{1.f,-1.f,-1.f,-1.f},{1.f,1.f,1.f,-1.f},
                            {1.f,-1.f,1.f,1.f},{1.f,1.f,-1.f,1.f}};
    int in_q = K >> 2;
    float w = W[(size_t)qm[c][cp] * 512 * in_q + (size_t)o * in_q + i] * qs[c][cp];
    E[idx] = f2bf(w);
}

// r8 twiddle tables: h=4 @0 (4) | h=32 @4 (32) | h=256 @36 (256) -> 292.
__device__ __forceinline__ void tabs_body(int blk, float2* __restrict__ gws,
                                          float* __restrict__ ph) {
    int i = blk * 256 + threadIdx.x;
    if (i < 292) {
        int off, denom;
        if (i < 4)       { off = 0;  denom = 16;   }
        else if (i < 36) { off = 4;  denom = 128;  }
        else             { off = 36; denom = 1024; }
        float a = (-PI_F) * (float)(i - off) / (float)denom;
        gws[i] = make_float2(cosf(a), sinf(a));
    }
    if (i <= 1024) {
        ph[i] = atanf(logf((float)i * (1.0f / 2048.0f) + 1e-6f));
    }
}

__global__ __launch_bounds__(256) void fat_prep(
        const float* __restrict__ query, const float* __restrict__ key,
        const float* __restrict__ value, u16* __restrict__ Acvt,
        const float* __restrict__ Wq, const float* __restrict__ Wk,
        const float* __restrict__ Wv, u16* __restrict__ Eq,
        u16* __restrict__ Ek, u16* __restrict__ Ev,
        const float* __restrict__ Wint, const float* __restrict__ Wfin,
        const float* __restrict__ Wout, u16* __restrict__ Eint,
        u16* __restrict__ Efin, u16* __restrict__ Eout,
        float2* __restrict__ gws, float* __restrict__ pht) {
    int b = blockIdx.x;
    if (b < 6144) {
        int ten = b >> 11, r = b & 2047;
        const float* in = (ten == 0) ? query : (ten == 1) ? key : value;
        cvt_body(r, in, Acvt + (size_t)ten * 8192 * 512);
    } else if (b < 18432) {
        int rb = b - 6144;
        int y = rb >> 12, r = rb & 4095;
        e3_body<9>(r, (y == 0) ? Wq : (y == 1) ? Wk : Wv,
                   (y == 0) ? Eq : (y == 1) ? Ek : Ev);
    } else if (b < 67584) {
        int rb = b - 18432;
        int y = rb >> 14, r = rb & 16383;
        e3_body<11>(r, (y == 0) ? Wint : (y == 1) ? Wfin : Wout,
                    (y == 0) ? Eint : (y == 1) ? Efin : Eout);
    } else {
        tabs_body(b - 67584, gws, pht);
    }
}

// ---------------------------------------------------------------------------
// Bias matvec: out[n] = sum_k v[k]*E[n][k] + badd[n]
// ---------------------------------------------------------------------------
__global__ __launch_bounds__(256) void matvec_E(const float* __restrict__ v,
                                                const u16* __restrict__ E,
                                                const float* __restrict__ badd,
                                                float* __restrict__ out) {
    int n    = (blockIdx.x * 256 + threadIdx.x) >> 6;
    int lane = threadIdx.x & 63;
    if (n >= 2048) return;
    const u16* row = E + (size_t)n * 2048;
    float s = 0.f;
    for (int j = lane; j < 2048; j += 64) s += v[j] * bf2f(row[j]);
#pragma unroll
    for (int o = 32; o; o >>= 1) s += __shfl_down(s, o, 64);
    if (lane == 0) out[n] = s + badd[n];
}

// ---------------------------------------------------------------------------
// bf16 MFMA GEMM body (m97 structure + XCD super-tiles). NBX=16, NBY=M/128.
// OUTMODE 0: bf16 [m][n]; 1: f32 [m][n]; 2: bf16 transposed [n][m]/[b][n][s]
// ---------------------------------------------------------------------------
template<int K, int OUTMODE, int NBY>
__device__ __forceinline__ void gemm_body(int bid, u16* As, u16* Bs,
                                          const u16* __restrict__ A,
                                          const u16* __restrict__ E,
                                          const float* __restrict__ bias,
                                          void* __restrict__ outp) {
    const int t    = threadIdx.x;
    const int lane = t & 63, wave = t >> 6;
    const int wr   = wave >> 1, wc = wave & 1;
    const int lr   = lane & 15, kg = lane >> 4;
    const int l7   = lr & 7;

    constexpr int SPX = (4 * (NBY / 4)) / 8;
    const int xcd = bid & 7, p = bid >> 3;
    const int st  = xcd * SPX + (p >> 4);
    const int w   = p & 15;
    const int bx  = (st & 3) * 4 + (w & 3);
    const int by  = (st >> 2) * 4 + (w >> 2);
    const int m0  = by * 128;
    const int n0  = bx * 128;

    f32x4 acc[4][4];
#pragma unroll
    for (int i = 0; i < 4; ++i)
#pragma unroll
        for (int j = 0; j < 4; ++j) acc[i][j] = (f32x4){0.f, 0.f, 0.f, 0.f};

    const int arow = wr * 64 + lr;
    const int brow = wc * 64 + lr;

    for (int k0 = 0; k0 < K; k0 += 64) {
#pragma unroll
        for (int c = 0; c < 4; ++c) {
            int idx = t + c * 256;
            int row = idx >> 3, sl = idx & 7;
            int gsl = sl ^ (row & 7);
            gl_lds16(A + (size_t)(m0 + row) * K + k0 + gsl * 8, &As[idx * 8]);
            gl_lds16(E + (size_t)(n0 + row) * K + k0 + gsl * 8, &Bs[idx * 8]);
        }
        __syncthreads();
#pragma unroll
        for (int ks = 0; ks < 2; ++ks) {
            const int slot = (ks * 4 + kg) ^ l7;
            s16x8 av[4], bv[4];
#pragma unroll
            for (int mi = 0; mi < 4; ++mi)
                av[mi] = *(const s16x8*)&As[(arow + mi * 16) * 64 + slot * 8];
#pragma unroll
            for (int ni = 0; ni < 4; ++ni)
                bv[ni] = *(const s16x8*)&Bs[(brow + ni * 16) * 64 + slot * 8];
#pragma unroll
            for (int mi = 0; mi < 4; ++mi)
#pragma unroll
                for (int ni = 0; ni < 4; ++ni)
                    acc[mi][ni] = __builtin_amdgcn_mfma_f32_16x16x32_bf16(
                        av[mi], bv[ni], acc[mi][ni], 0, 0, 0);
        }
        __syncthreads();
    }

#pragma unroll
    for (int ni = 0; ni < 4; ++ni) {
        int n = n0 + wc * 64 + ni * 16 + lr;
        float bvl = bias ? bias[n] : 0.0f;
#pragma unroll
        for (int mi = 0; mi < 4; ++mi) {
#pragma unroll
            for (int r = 0; r < 4; ++r) {
                int m = m0 + wr * 64 + mi * 16 + kg * 4 + r;
                float val = acc[mi][ni][r] + bvl;
                if constexpr (OUTMODE == 0) {
                    ((u16*)outp)[(size_t)m * 2048 + n] = f2bf(val);
                } else if constexpr (OUTMODE == 1) {
                    ((float*)outp)[(size_t)m * 2048 + n] = val;
                } else {
                    int b = m >> 11, s = m & 2047;
                    ((u16*)outp)[((size_t)b * 2048 + n) * 2048 + s] = f2bf(val);
                }
            }
        }
    }
}

template<int K, int OUTMODE, int NBY>
__global__ __launch_bounds__(256) void gemm2(const u16* __restrict__ A,
                                             const u16* __restrict__ E,
                                             const float* __restrict__ bias,
                                             void* __restrict__ outp) {
    __shared__ u16 As[128 * 64];
    __shared__ u16 Bs[128 * 64];
    gemm_body<K, OUTMODE, NBY>(blockIdx.x, As, Bs, A, E, bias, outp);
}

// Layer-A fat kernel: combine1 (256, FIRST) + projQ (1024) + projK (1024)
__global__ __launch_bounds__(256) void gemm_fatA(const u16* __restrict__ Aq,
                                                 const u16* __restrict__ Eq,
                                                 const float* __restrict__ bq,
                                                 void* __restrict__ Qt,
                                                 const u16* __restrict__ Ak,
                                                 const u16* __restrict__ Ek,
                                                 const float* __restrict__ bk,
                                                 void* __restrict__ Kt,
                                                 const u16* __restrict__ Efin,
                                                 const u16* __restrict__ EintT,
                                                 void* __restrict__ T1T) {
    __shared__ u16 As[128 * 64];
    __shared__ u16 Bs[128 * 64];
    int bid = blockIdx.x;
    if (bid < 256) {
        gemm_body<2048, 2, 16>(bid, As, Bs, Efin, EintT, nullptr, T1T);
    } else {
        int pid = bid - 256;
        if (pid < 1024)
            gemm_body<512, 2, 64>(pid, As, Bs, Aq, Eq, bq, Qt);
        else
            gemm_body<512, 2, 64>(pid - 1024, As, Bs, Ak, Ek, bk, Kt);
    }
}

// ---------------------------------------------------------------------------
// In-place FFT, bitrev input -> natural output.
// Twiddle-free radix-4 (stages 0-1) + radix-8 passes (stages 2-4, 5-7, 8-10).
// ---------------------------------------------------------------------------
template<int LH, int OFF>
__device__ __forceinline__ void r8pass(float* re, float* im,
                                       const float2* __restrict__ wt, int t) {
    constexpr int h = 1 << LH;
    __syncthreads();
    const int j  = t & (h - 1);
    const int i0 = ((t >> LH) << (LH + 3)) | j;
    const float2 w = wt[OFF + j];               // t3 = cis(-pi*j/(4h))
    const float t2r = w.x * w.x - w.y * w.y;    // t2 = t3^2
    const float t2i = 2.f * w.x * w.y;
    const float t1r = t2r * t2r - t2i * t2i;    // t1 = t3^4
    const float t1i = 2.f * t2r * t2i;
    const float S = 0.70710678118654752f;
    const float Ac = S * (w.x + w.y);           // t3*cis(-pi/4) = (Ac, Bc)
    const float Bc = S * (w.y - w.x);           // t3*cis(-3pi/4) = (Bc, -Ac)

    float xr[8], xi[8];
    int p[8];
#pragma unroll
    for (int k = 0; k < 8; ++k) {
        p[k] = PD(i0 + k * h);
        xr[k] = re[p[k]]; xi[k] = im[p[k]];
    }
#pragma unroll
    for (int kp = 0; kp < 8; kp += 2) {
        float tr = t1r * xr[kp + 1] - t1i * xi[kp + 1];
        float ti = t1r * xi[kp + 1] + t1i * xr[kp + 1];
        float ar = xr[kp], ai = xi[kp];
        xr[kp] = ar + tr;     xi[kp] = ai + ti;
        xr[kp + 1] = ar - tr; xi[kp + 1] = ai - ti;
    }
#pragma unroll
    for (int q = 0; q < 2; ++q) {
        int b0 = q * 4;
        {
            float tr = t2r * xr[b0 + 2] - t2i * xi[b0 + 2];
            float ti = t2r * xi[b0 + 2] + t2i * xr[b0 + 2];
            float ar = xr[b0], ai = xi[b0];
            xr[b0] = ar + tr;     xi[b0] = ai + ti;
            xr[b0 + 2] = ar - tr; xi[b0 + 2] = ai - ti;
        }
        {
            float tr = t2i * xr[b0 + 3] + t2r * xi[b0 + 3];
            float ti = t2i * xi[b0 + 3] - t2r * xr[b0 + 3];
            float ar = xr[b0 + 1], ai = xi[b0 + 1];
            xr[b0 + 1] = ar + tr; xi[b0 + 1] = ai + ti;
            xr[b0 + 3] = ar - tr; xi[b0 + 3] = ai - ti;
        }
    }
    {
        float tr = w.x * xr[4] - w.y * xi[4];
        float ti = w.x * xi[4] + w.y * xr[4];
        float ar = xr[0], ai = xi[0];
        xr[0] = ar + tr; xi[0] = ai + ti;
        xr[4] = ar - tr; xi[4] = ai - ti;
    }
    {
        float tr = Ac * xr[5] - Bc * xi[5];
        float ti = Ac * xi[5] + Bc * xr[5];
        float ar = xr[1], ai = xi[1];
        xr[1] = ar + tr; xi[1] = ai + ti;
        xr[5] = ar - tr; xi[5] = ai - ti;
    }
    {
        float tr = w.y * xr[6] + w.x * xi[6];
        float ti = w.y * xi[6] - w.x * xr[6];
        float ar = xr[2], ai = xi[2];
        xr[2] = ar + tr; xi[2] = ai + ti;
        xr[6] = ar - tr; xi[6] = ai - ti;
    }
    {
        float tr = Bc * xr[7] + Ac * xi[7];
        float ti = Bc * xi[7] - Ac * xr[7];
        float ar = xr[3], ai = xi[3];
        xr[3] = ar + tr; xi[3] = ai + ti;
        xr[7] = ar - tr; xi[7] = ai - ti;
    }
#pragma unroll
    for (int k = 0; k < 8; ++k) { re[p[k]] = xr[k]; im[p[k]] = xi[k]; }
}

__device__ void fft2048(float* re, float* im, const float2* __restrict__ wt, int t) {
    __syncthreads();   // input scatter complete
#pragma unroll
    for (int u = 0; u < 2; ++u) {
        int i0 = (t + u * 256) << 2;
        int p0 = PD(i0);
        float x0r = re[p0],     x0i = im[p0];
        float x1r = re[p0 + 1], x1i = im[p0 + 1];
        float x2r = re[p0 + 2], x2i = im[p0 + 2];
        float x3r = re[p0 + 3], x3i = im[p0 + 3];
        float ar = x0r + x1r, ai = x0i + x1i;
        float br = x0r - x1r, bi = x0i - x1i;
        float cr = x2r + x3r, ci = x2i + x3i;
        float dr = x2r - x3r, di = x2i - x3i;
        re[p0]     = ar + cr; im[p0]     = ai + ci;
        re[p0 + 2] = ar - cr; im[p0 + 2] = ai - ci;
        re[p0 + 1] = br + di; im[p0 + 1] = bi - dr;
        re[p0 + 3] = br - di; im[p0 + 3] = bi + dr;
    }
    r8pass<2, 0>(re, im, wt, t);
    r8pass<5, 4>(re, im, wt, t);
    r8pass<8, 36>(re, im, wt, t);
    __syncthreads();
}

// ---------------------------------------------------------------------------
// Spectral body: 2 channels, packed FFTs; writes WEIGHTS to Wt.
// Wt may alias Qt: each block reads ONLY its own 2 channels (fully consumed
// before the final write) and writes ONLY those same 2 channels.
// ---------------------------------------------------------------------------
__device__ void spectral_body(int sbid, float* zre, float* zim, float2* wt,
                              const u16* __restrict__ Qt,
                              const u16* __restrict__ Kt,
                              u16* __restrict__ Wt,
                              const float* __restrict__ alpha,
                              const float2* __restrict__ gws,
                              const float* __restrict__ gph) {
    const int t  = threadIdx.x;
    const int b  = sbid >> 10;
    const int cp = sbid & 1023;
    const int c0 = cp * 2;
    const size_t base0 = ((size_t)b * 2048 + c0) * 2048;
    const size_t base1 = base0 + 2048;

    for (int i = t; i < 292; i += 256) wt[i] = gws[i];

    float ph[4];
    float PH1r[4], PH1i[4], PH2r[4], PH2i[4];
    float ph24 = 0.f, PH24_1 = 0.f, PH24_2 = 0.f;

#pragma unroll
    for (int ch = 0; ch < 2; ++ch) {
        const size_t base = ch ? base1 : base0;
        const u16* Qp = Qt + base;
        const u16* Kp = Kt + base;
        __syncthreads();
#pragma unroll
        for (int u = 0; u < 8; ++u) {
            int s = t + u * 256;
            int r = __brev((unsigned)s) >> 21;
            zre[PD(r)] = bf2f(Qp[s]);
            zim[PD(r)] = bf2f(Kp[s]);
        }
        fft2048(zre, zim, wt, t);
        const float ac = alpha[c0 + ch];
#pragma unroll
        for (int u = 0; u < 4; ++u) {
            int k = t + u * 256;
            int m = (2048 - k) & 2047;
            float ar = zre[PD(k)], ai = zim[PD(k)];
            float br = zre[PD(m)], bi = zim[PD(m)];
            float qr = 0.5f * (ar + br), qi = 0.5f * (ai - bi);
            float kr = 0.5f * (ai + bi), ki = 0.5f * (br - ar);
            float cr = qr * kr + qi * ki;
            float ci = qi * kr - qr * ki;
            if (ch == 0) ph[u] = gph[min(k, 2048 - k)];
            float fr, fi;
            __sincosf(ph[u] * ac, &fi, &fr);
            float Pkr = cr * fr - ci * fi, Pki = cr * fi + ci * fr;
            float qr2 = 0.5f * (br + ar), qi2 = 0.5f * (bi - ai);
            float kr2 = 0.5f * (bi + ai), ki2 = 0.5f * (ar - br);
            float cr2 = qr2 * kr2 + qi2 * ki2;
            float ci2 = qi2 * kr2 - qr2 * ki2;
            float Pmr = cr2 * fr - ci2 * fi, Pmi = cr2 * fi + ci2 * fr;
            float hr = 0.5f * (Pkr + Pmr), hi = 0.5f * (Pki - Pmi);
            if (ch == 0) { PH1r[u] = hr; PH1i[u] = hi; }
            else         { PH2r[u] = hr; PH2i[u] = hi; }
        }
        if (t == 0) {
            float ar = zre[PD(1024)], ai = zim[PD(1024)];
            float cr = ar * ai;
            if (ch == 0) ph24 = gph[1024];
            float fr, fi;
            __sincosf(ph24 * ac, &fi, &fr);
            if (ch == 0) PH24_1 = cr * fr; else PH24_2 = cr * fr;
        }
    }

    __syncthreads();
#pragma unroll
    for (int u = 0; u < 4; ++u) {
        int k = t + u * 256;
        int m = (2048 - k) & 2047;
        int rk = __brev((unsigned)k) >> 21;
        int rm = __brev((unsigned)m) >> 21;
        zre[PD(rk)] = PH1r[u] - PH2i[u];
        zim[PD(rk)] = PH1i[u] + PH2r[u];
        zre[PD(rm)] = PH1r[u] + PH2i[u];
        zim[PD(rm)] = PH2r[u] - PH1i[u];
    }
    if (t == 0) {
        zre[PD(1)] = PH24_1;
        zim[PD(1)] = PH24_2;
    }
    fft2048(zre, zim, wt, t);

#pragma unroll
    for (int u = 0; u < 8; ++u) {
        int s = t + u * 256;
        int j = (2048 - s) & 2047;
        Wt[base0 + s] = f2bf(zre[PD(j)] * (1.0f / 2048.0f));
        Wt[base1 + s] = f2bf(zim[PD(j)] * (1.0f / 2048.0f));
    }
}

// Layer-B fat kernel: combine2 (256, FIRST — full kernel window to finish) +
// spectral (4096) + projV (1024) interleaved 4:1. Wt aliases Qt (in-place),
// so Eout/T1T stay live for combine2.
__global__ __launch_bounds__(256) void fat_specv(const u16* __restrict__ Qt,
                                                 const u16* __restrict__ Kt,
                                                 u16* __restrict__ Wt,
                                                 const float* __restrict__ alpha,
                                                 const float2* __restrict__ gws,
                                                 const float* __restrict__ gph,
                                                 const u16* __restrict__ Av,
                                                 const u16* __restrict__ Ev,
                                                 const float* __restrict__ bvb,
                                                 void* __restrict__ Vt,
                                                 const u16* __restrict__ Eout,
                                                 const u16* __restrict__ T1T,
                                                 void* __restrict__ Ecomb) {
    __shared__ __align__(16) char smem[32768];
    int bid = blockIdx.x;
    if (bid < 256) {
        gemm_body<2048, 0, 16>(bid, (u16*)smem, (u16*)(smem + 16384),
                               Eout, T1T, nullptr, Ecomb);
        return;
    }
    bid -= 256;
    if (bid % 5 == 4) {
        gemm_body<512, 2, 64>(bid / 5, (u16*)smem, (u16*)(smem + 16384),
                              Av, Ev, bvb, Vt);
    } else {
        int sbid = (bid / 5) * 4 + (bid % 5);
        spectral_body(sbid, (float*)smem, (float*)(smem + 8960),
                      (float2*)(smem + 17920), Qt, Kt, Wt, alpha, gws, gph);
    }
}

// ---------------------------------------------------------------------------
// Plain transpose (EintT) and fused multiply-transpose (attn = (W .* V)^T)
// ---------------------------------------------------------------------------
__global__ __launch_bounds__(256) void transpose_k(const u16* __restrict__ in,
                                                   u16* __restrict__ out) {
    __shared__ u16 tile[32][33];
    int b = blockIdx.z;
    int c0 = blockIdx.x * 32, s0 = blockIdx.y * 32;
    int tx = threadIdx.x, ty = threadIdx.y;
#pragma unroll
    for (int dy = 0; dy < 32; dy += 8)
        tile[ty + dy][tx] = in[((size_t)b * 2048 + c0 + ty + dy) * 2048 + s0 + tx];
    __syncthreads();
#pragma unroll
    for (int dy = 0; dy < 32; dy += 8)
        out[((size_t)b * 2048 + s0 + ty + dy) * 2048 + c0 + tx] = tile[tx][ty + dy];
}

__global__ __launch_bounds__(256) void transpose_mul(const u16* __restrict__ W,
                                                     const u16* __restrict__ V,
                                                     u16* __restrict__ out) {
    __shared__ u16 tile[32][33];
    int b = blockIdx.z;
    int c0 = blockIdx.x * 32, s0 = blockIdx.y * 32;
    int tx = threadIdx.x, ty = threadIdx.y;
#pragma unroll
    for (int dy = 0; dy < 32; dy += 8) {
        size_t idx = ((size_t)b * 2048 + c0 + ty + dy) * 2048 + s0 + tx;
        tile[ty + dy][tx] = f2bf(bf2f(W[idx]) * bf2f(V[idx]));
    }
    __syncthreads();
#pragma unroll
    for (int dy = 0; dy < 32; dy += 8)
        out[((size_t)b * 2048 + s0 + ty + dy) * 2048 + c0 + tx] = tile[tx][ty + dy];
}

// ---------------------------------------------------------------------------
extern "C" void kernel_launch(void* const* d_in, const int* in_sizes, int n_in,
                              void* d_out, int out_size, void* d_ws, size_t ws_size,
                              hipStream_t stream) {
    const float* query = (const float*)d_in[0];
    const float* key   = (const float*)d_in[1];
    const float* value = (const float*)d_in[2];
    const float* Wq    = (const float*)d_in[3];
    const float* bq    = (const float*)d_in[4];
    const float* Wk    = (const float*)d_in[5];
    const float* bk    = (const float*)d_in[6];
    const float* Wv    = (const float*)d_in[7];
    const float* bv    = (const float*)d_in[8];
    const float* alpha = (const float*)d_in[9];
    const float* Wint  = (const float*)d_in[10];
    const float* bint  = (const float*)d_in[11];
    const float* Wfin  = (const float*)d_in[12];
    const float* bfin  = (const float*)d_in[13];
    const float* Wout  = (const float*)d_in[14];
    const float* bout  = (const float*)d_in[15];

    char* ws = (char*)d_ws;
    size_t off = 0;
    auto alloc = [&](size_t bytes) -> void* {
        void* p = ws + off;
        off += (bytes + 255) & ~(size_t)255;
        return p;
    };
    u16* Eq   = (u16*)alloc((size_t)2048 * 512 * 2);
    u16* Ek   = (u16*)alloc((size_t)2048 * 512 * 2);
    u16* Ev   = (u16*)alloc((size_t)2048 * 512 * 2);
    u16* Eint = (u16*)alloc((size_t)2048 * 2048 * 2);   // becomes Ecomb
    u16* Efin = (u16*)alloc((size_t)2048 * 2048 * 2);
    u16* Eout = (u16*)alloc((size_t)2048 * 2048 * 2);
    u16* EintT= (u16*)alloc((size_t)2048 * 2048 * 2);
    u16* T1T  = (u16*)alloc((size_t)2048 * 2048 * 2);
    u16* Qt   = (u16*)alloc((size_t)4 * 2048 * 2048 * 2);
    u16* Kt   = (u16*)alloc((size_t)4 * 2048 * 2048 * 2);
    u16* Vt   = (u16*)alloc((size_t)4 * 2048 * 2048 * 2);
    u16* attn = (u16*)alloc((size_t)8192 * 2048 * 2);
    float2* gws = (float2*)alloc(292 * 8);
    float*  pht = (float*)alloc(1025 * 4);
    float*  bv1 = (float*)alloc(2048 * 4);
    float*  bv2 = (float*)alloc(2048 * 4);
    u16* Ecomb = Eint;  // Eint (weights form) dead after EintT is built
    u16* Wt    = Qt;    // in-place: spectral reads its own channels fully
                        // before writing; Eout/T1T stay live for combine2
    u16* Aq = attn;
    u16* Ak = attn + (size_t)8192 * 512;
    u16* Av = attn + (size_t)8192 * 1024;

    // one fused prep dispatch: cvt x3, E<9> x3, E<11> x3, tables
    fat_prep<<<67589, 256, 0, stream>>>(query, key, value, Aq,
                                        Wq, Wk, Wv, Eq, Ek, Ev,
                                        Wint, Wfin, Wout, Eint, Efin, Eout,
                                        gws, pht);

    dim3 gt1(64, 64, 1);
    transpose_k<<<gt1, dim3(32, 8), 0, stream>>>(Eint, EintT);

    // Layer A: combine1 (first) + projQ + projK
    gemm_fatA<<<2304, 256, 0, stream>>>(Aq, Eq, bq, Qt, Ak, Ek, bk, Kt,
                                        Efin, EintT, T1T);

    // combined bias: bv2 = (bint*Efin^T + bfin)*Eout^T + bout
    matvec_E<<<512, 256, 0, stream>>>(bint, Efin, bfin, bv1);
    matvec_E<<<512, 256, 0, stream>>>(bv1,  Eout, bout, bv2);

    // Layer B: combine2 (first) + spectral (in-place over Qt) + projV
    fat_specv<<<5376, 256, 0, stream>>>(Qt, Kt, Wt, alpha, gws, pht,
                                        Av, Ev, bv, Vt, Eout, T1T, Ecomb);

    // attn[(b,s)][c] = W[b][c][s] * V[b][c][s]
    dim3 gt(64, 64, 4);
    transpose_mul<<<gt, dim3(32, 8), 0, stream>>>(Wt, Vt, attn);

    // single fused trailing linear
    gemm2<2048, 1, 64><<<1024, 256, 0, stream>>>(attn, Ecomb, bv2, (float*)d_out);
}